// Round 1
// baseline (5708.844 us; speedup 1.0000x reference)
//
#include <hip/hip_runtime.h>

#define FEAT 128
#define BN_EPS 1e-5f

// ---------------- weight prep: Wt[k][n] = k<128 ? Wl[n][k] : Wr[n][k-128] ----
__global__ void prep_weights(const float* __restrict__ W1l, const float* __restrict__ W1r,
                             const float* __restrict__ W2l, const float* __restrict__ W2r,
                             float* __restrict__ Wt1, float* __restrict__ Wt2) {
    int tid = blockIdx.x * blockDim.x + threadIdx.x;
    if (tid < 256 * 128) {
        int k = tid >> 7, n = tid & 127;
        Wt1[tid] = (k < 128) ? W1l[n * 128 + k] : W1r[n * 128 + (k - 128)];
    }
    if (tid < 256 * 64) {
        int k = tid >> 6, n = tid & 63;
        Wt2[tid] = (k < 128) ? W2l[n * 128 + k] : W2r[n * 128 + (k - 128)];
    }
}

// ---------------- degree count ----------------------------------------------
__global__ void count_deg(const int* __restrict__ dst, int E, float* __restrict__ deg) {
    int i = blockIdx.x * blockDim.x + threadIdx.x;
    if (i < E) atomicAdd(&deg[dst[i]], 1.0f);
}

// ---------------- scatter-add messages: 32 threads per edge, float4 each ----
__global__ void scatter_add_128(const float* __restrict__ feat,
                                const int* __restrict__ src, const int* __restrict__ dst,
                                int E, float* __restrict__ agg) {
    int gid = blockIdx.x * blockDim.x + threadIdx.x;
    int e = gid >> 5;
    if (e >= E) return;
    int lane = gid & 31;
    int s = src[e], d = dst[e];
    float4 v = *(const float4*)(feat + (size_t)s * FEAT + lane * 4);
    float* o = agg + (size_t)d * FEAT + lane * 4;
    atomicAdd(o + 0, v.x);
    atomicAdd(o + 1, v.y);
    atomicAdd(o + 2, v.z);
    atomicAdd(o + 3, v.w);
}

// ---------------- fused SAGE layer: C[N,NOUT] = [mean_agg | x] @ Wt + epilogue
// TM=64 nodes per block, BK=16, 256 threads, micro-tile 4 nodes x (NOUT/16) outs
template <int NOUT, bool BN_RELU>
__global__ __launch_bounds__(256) void sage_layer(
    const float* __restrict__ agg, const float* __restrict__ xin,
    const float* __restrict__ deg, const float* __restrict__ Wt,
    const float* __restrict__ bias,
    const float* __restrict__ g, const float* __restrict__ bt,
    const float* __restrict__ mu, const float* __restrict__ var,
    float* __restrict__ out, int N)
{
    constexpr int TM = 64;
    constexpr int BK = 16;
    constexpr int TN = NOUT / 16;  // 8 (layer1) or 4 (layer2)

    __shared__ __align__(16) float As[BK][TM];
    __shared__ __align__(16) float Bs[BK * NOUT];
    __shared__ float invd[TM];

    const int tid = threadIdx.x;
    const int m0 = blockIdx.x * TM;

    if (tid < TM) {
        int node = m0 + tid;
        float dg = (node < N) ? deg[node] : 1.0f;
        invd[tid] = 1.0f / fmaxf(dg, 1.0f);
    }

    const int tm = tid & 15;   // node group for compute
    const int tn = tid >> 4;   // out group (0..15)

    float acc[4][TN];
#pragma unroll
    for (int i = 0; i < 4; i++)
#pragma unroll
        for (int j = 0; j < TN; j++) acc[i][j] = 0.f;

    const int lm = tid >> 2;         // 0..63 node for A staging
    const int lk = (tid & 3) * 4;    // 0,4,8,12
    const int node = m0 + lm;
    const bool mvalid = node < N;

    __syncthreads();  // invd ready

    for (int kc = 0; kc < 256; kc += BK) {
        // ---- stage A tile (k-major) ----
        float4 av = make_float4(0.f, 0.f, 0.f, 0.f);
        if (mvalid) {
            int k = kc + lk;
            if (k < 128) {
                av = *(const float4*)&agg[(size_t)node * FEAT + k];
                float s = invd[lm];
                av.x *= s; av.y *= s; av.z *= s; av.w *= s;
            } else {
                av = *(const float4*)&xin[(size_t)node * FEAT + (k - 128)];
            }
        }
        As[lk + 0][lm] = av.x;
        As[lk + 1][lm] = av.y;
        As[lk + 2][lm] = av.z;
        As[lk + 3][lm] = av.w;

        // ---- stage B tile: contiguous BK*NOUT floats from Wt ----
        {
            const float4* src4 = (const float4*)(Wt + (size_t)kc * NOUT);
            float4* dst4 = (float4*)Bs;
            constexpr int NV = BK * NOUT / 4;  // 512 or 256
#pragma unroll
            for (int r = 0; r < NV / 256; r++)
                dst4[tid + r * 256] = src4[tid + r * 256];
        }
        __syncthreads();

#pragma unroll
        for (int kk = 0; kk < BK; kk++) {
            float4 a = *(const float4*)&As[kk][tm * 4];
            float b[TN];
            const float4* brow = (const float4*)&Bs[kk * NOUT + tn * TN];
#pragma unroll
            for (int j4 = 0; j4 < TN / 4; j4++) {
                float4 t = brow[j4];
                b[j4 * 4 + 0] = t.x; b[j4 * 4 + 1] = t.y;
                b[j4 * 4 + 2] = t.z; b[j4 * 4 + 3] = t.w;
            }
#pragma unroll
            for (int j = 0; j < TN; j++) {
                acc[0][j] += a.x * b[j];
                acc[1][j] += a.y * b[j];
                acc[2][j] += a.z * b[j];
                acc[3][j] += a.w * b[j];
            }
        }
        __syncthreads();
    }

    // ---- epilogue: bias (+ BN + ReLU) ----
#pragma unroll
    for (int i = 0; i < 4; i++) {
        int m = m0 + tm * 4 + i;
        if (m >= N) continue;
        float vals[TN];
#pragma unroll
        for (int j = 0; j < TN; j++) {
            int n = tn * TN + j;
            float v = acc[i][j] + bias[n];
            if (BN_RELU) {
                float rs = rsqrtf(var[n] + BN_EPS);
                float scale = rs * g[n];
                v = v * scale + (bt[n] - mu[n] * scale);
                v = fmaxf(v, 0.f);
            }
            vals[j] = v;
        }
#pragma unroll
        for (int j4 = 0; j4 < TN / 4; j4++) {
            float4 v4 = make_float4(vals[j4 * 4 + 0], vals[j4 * 4 + 1],
                                    vals[j4 * 4 + 2], vals[j4 * 4 + 3]);
            *(float4*)&out[(size_t)m * NOUT + tn * TN + j4 * 4] = v4;
        }
    }
}

extern "C" void kernel_launch(void* const* d_in, const int* in_sizes, int n_in,
                              void* d_out, int out_size, void* d_ws, size_t ws_size,
                              hipStream_t stream) {
    const float* x     = (const float*)d_in[0];
    const int*   edge  = (const int*)d_in[1];
    const float* W1l   = (const float*)d_in[2];
    const float* b1    = (const float*)d_in[3];
    const float* W1r   = (const float*)d_in[4];
    const float* gamma = (const float*)d_in[5];
    const float* beta  = (const float*)d_in[6];
    const float* mean  = (const float*)d_in[7];
    const float* var   = (const float*)d_in[8];
    const float* W2l   = (const float*)d_in[9];
    const float* b2    = (const float*)d_in[10];
    const float* W2r   = (const float*)d_in[11];

    const int N = in_sizes[0] / FEAT;
    const int E = in_sizes[1] / 2;
    const int* srcI = edge;
    const int* dstI = edge + E;

    // workspace layout (floats): agg[N*128] | h[N*128] | deg[N] | Wt1[32768] | Wt2[16384]
    float* agg = (float*)d_ws;
    float* h   = agg + (size_t)N * FEAT;
    float* deg = h + (size_t)N * FEAT;
    float* Wt1 = deg + N;
    float* Wt2 = Wt1 + 256 * 128;

    float* outp = (float*)d_out;

    hipMemsetAsync(agg, 0, (size_t)N * FEAT * sizeof(float), stream);
    hipMemsetAsync(deg, 0, (size_t)N * sizeof(float), stream);

    prep_weights<<<128, 256, 0, stream>>>(W1l, W1r, W2l, W2r, Wt1, Wt2);
    count_deg<<<(E + 255) / 256, 256, 0, stream>>>(dstI, E, deg);

    // layer 1 aggregation + fused layer
    {
        long long total = (long long)E * 32;
        int blocks = (int)((total + 255) / 256);
        scatter_add_128<<<blocks, 256, 0, stream>>>(x, srcI, dstI, E, agg);
    }
    sage_layer<128, true><<<(N + 63) / 64, 256, 0, stream>>>(
        agg, x, deg, Wt1, b1, gamma, beta, mean, var, h, N);

    // layer 2
    hipMemsetAsync(agg, 0, (size_t)N * FEAT * sizeof(float), stream);
    {
        long long total = (long long)E * 32;
        int blocks = (int)((total + 255) / 256);
        scatter_add_128<<<blocks, 256, 0, stream>>>(h, srcI, dstI, E, agg);
    }
    sage_layer<64, false><<<(N + 63) / 64, 256, 0, stream>>>(
        agg, h, deg, Wt2, b2, gamma, beta, mean, var, outp, N);
}

// Round 2
// 801.248 us; speedup vs baseline: 7.1249x; 7.1249x over previous
//
#include <hip/hip_runtime.h>

#define FEAT 128
#define BN_EPS 1e-5f

// ---------------- weight prep: Wt[k][n] = k<128 ? Wl[n][k] : Wr[n][k-128] ----
__global__ void prep_weights(const float* __restrict__ W1l, const float* __restrict__ W1r,
                             const float* __restrict__ W2l, const float* __restrict__ W2r,
                             float* __restrict__ Wt1, float* __restrict__ Wt2) {
    int tid = blockIdx.x * blockDim.x + threadIdx.x;
    if (tid < 256 * 128) {
        int k = tid >> 7, n = tid & 127;
        Wt1[tid] = (k < 128) ? W1l[n * 128 + k] : W1r[n * 128 + (k - 128)];
    }
    if (tid < 256 * 64) {
        int k = tid >> 6, n = tid & 63;
        Wt2[tid] = (k < 128) ? W2l[n * 128 + k] : W2r[n * 128 + (k - 128)];
    }
}

// ---------------- degree histogram (uint) -----------------------------------
__global__ void count_deg(const int* __restrict__ dst, int E, unsigned* __restrict__ degi) {
    int i = blockIdx.x * blockDim.x + threadIdx.x;
    if (i < E) atomicAdd(&degi[dst[i]], 1u);
}

// ---------------- hierarchical exclusive scan over degi ---------------------
// k1: per-block (256) exclusive-within-block into row_start; block total -> partials
__global__ void scan_block(const unsigned* __restrict__ degi, unsigned* __restrict__ excl,
                           unsigned* __restrict__ partials, int N) {
    __shared__ unsigned buf[256];
    int i = blockIdx.x * 256 + threadIdx.x;
    unsigned v = (i < N) ? degi[i] : 0u;
    buf[threadIdx.x] = v;
    __syncthreads();
    for (int off = 1; off < 256; off <<= 1) {
        unsigned t = (threadIdx.x >= (unsigned)off) ? buf[threadIdx.x - off] : 0u;
        __syncthreads();
        buf[threadIdx.x] += t;
        __syncthreads();
    }
    if (i < N) excl[i] = buf[threadIdx.x] - v;
    if (threadIdx.x == 255) partials[blockIdx.x] = buf[255];
}

// k2: single-block exclusive scan of partials (nb <= 1024)
__global__ void scan_partials(unsigned* __restrict__ partials, int nb) {
    __shared__ unsigned buf[1024];
    unsigned v = ((int)threadIdx.x < nb) ? partials[threadIdx.x] : 0u;
    buf[threadIdx.x] = v;
    __syncthreads();
    for (int off = 1; off < 1024; off <<= 1) {
        unsigned t = (threadIdx.x >= (unsigned)off) ? buf[threadIdx.x - off] : 0u;
        __syncthreads();
        buf[threadIdx.x] += t;
        __syncthreads();
    }
    if ((int)threadIdx.x < nb) partials[threadIdx.x] = buf[threadIdx.x] - v;
}

// k3: add block offsets; duplicate into write_ptr; set row_start[N]=E
__global__ void scan_finish(unsigned* __restrict__ row_start, unsigned* __restrict__ write_ptr,
                            const unsigned* __restrict__ partials, int N, int E) {
    int i = blockIdx.x * blockDim.x + threadIdx.x;
    if (i < N) {
        unsigned r = row_start[i] + partials[i >> 8];
        row_start[i] = r;
        write_ptr[i] = r;
    }
    if (i == 0) row_start[N] = (unsigned)E;
}

// ---------------- CSR fill: one int atomic per edge -------------------------
__global__ void fill_csr(const int* __restrict__ src, const int* __restrict__ dst, int E,
                         unsigned* __restrict__ write_ptr, unsigned* __restrict__ csr_src) {
    int e = blockIdx.x * blockDim.x + threadIdx.x;
    if (e >= E) return;
    unsigned pos = atomicAdd(&write_ptr[dst[e]], 1u);
    csr_src[pos] = (unsigned)src[e];
}

// ---------------- gather + mean: one wave (64 lanes) per node ---------------
__global__ __launch_bounds__(256) void gather_mean(const float* __restrict__ feat,
                                                   const unsigned* __restrict__ row_start,
                                                   const unsigned* __restrict__ csr_src,
                                                   float* __restrict__ agg, int N) {
    int node = (blockIdx.x * blockDim.x + threadIdx.x) >> 6;
    int lane = threadIdx.x & 63;
    if (node >= N) return;
    unsigned s0 = row_start[node], s1 = row_start[node + 1];
    float2 acc = make_float2(0.f, 0.f);
    for (unsigned i = s0; i < s1; i++) {
        unsigned s = csr_src[i];
        float2 v = *(const float2*)(feat + (size_t)s * FEAT + lane * 2);
        acc.x += v.x; acc.y += v.y;
    }
    float inv = (s1 > s0) ? 1.0f / (float)(s1 - s0) : 0.f;
    acc.x *= inv; acc.y *= inv;
    *(float2*)(agg + (size_t)node * FEAT + lane * 2) = acc;
}

// ---------------- fused SAGE layer: C[N,NOUT] = [agg | x] @ Wt + epilogue ----
template <int NOUT, bool BN_RELU>
__global__ __launch_bounds__(256) void sage_layer(
    const float* __restrict__ agg, const float* __restrict__ xin,
    const float* __restrict__ Wt, const float* __restrict__ bias,
    const float* __restrict__ g, const float* __restrict__ bt,
    const float* __restrict__ mu, const float* __restrict__ var,
    float* __restrict__ out, int N)
{
    constexpr int TM = 64;
    constexpr int BK = 16;
    constexpr int TN = NOUT / 16;  // 8 (layer1) or 4 (layer2)

    __shared__ __align__(16) float As[BK][TM];
    __shared__ __align__(16) float Bs[BK * NOUT];

    const int tid = threadIdx.x;
    const int m0 = blockIdx.x * TM;

    const int tm = tid & 15;   // node group for compute
    const int tn = tid >> 4;   // out group (0..15)

    float acc[4][TN];
#pragma unroll
    for (int i = 0; i < 4; i++)
#pragma unroll
        for (int j = 0; j < TN; j++) acc[i][j] = 0.f;

    const int lm = tid >> 2;         // 0..63 node for A staging
    const int lk = (tid & 3) * 4;    // 0,4,8,12
    const int node = m0 + lm;
    const bool mvalid = node < N;

    for (int kc = 0; kc < 256; kc += BK) {
        // ---- stage A tile (k-major) ----
        float4 av = make_float4(0.f, 0.f, 0.f, 0.f);
        if (mvalid) {
            int k = kc + lk;
            if (k < 128) {
                av = *(const float4*)&agg[(size_t)node * FEAT + k];
            } else {
                av = *(const float4*)&xin[(size_t)node * FEAT + (k - 128)];
            }
        }
        As[lk + 0][lm] = av.x;
        As[lk + 1][lm] = av.y;
        As[lk + 2][lm] = av.z;
        As[lk + 3][lm] = av.w;

        // ---- stage B tile: contiguous BK*NOUT floats from Wt ----
        {
            const float4* src4 = (const float4*)(Wt + (size_t)kc * NOUT);
            float4* dst4 = (float4*)Bs;
            constexpr int NV = BK * NOUT / 4;  // 512 or 256
#pragma unroll
            for (int r = 0; r < NV / 256; r++)
                dst4[tid + r * 256] = src4[tid + r * 256];
        }
        __syncthreads();

#pragma unroll
        for (int kk = 0; kk < BK; kk++) {
            float4 a = *(const float4*)&As[kk][tm * 4];
            float b[TN];
            const float4* brow = (const float4*)&Bs[kk * NOUT + tn * TN];
#pragma unroll
            for (int j4 = 0; j4 < TN / 4; j4++) {
                float4 t = brow[j4];
                b[j4 * 4 + 0] = t.x; b[j4 * 4 + 1] = t.y;
                b[j4 * 4 + 2] = t.z; b[j4 * 4 + 3] = t.w;
            }
#pragma unroll
            for (int j = 0; j < TN; j++) {
                acc[0][j] += a.x * b[j];
                acc[1][j] += a.y * b[j];
                acc[2][j] += a.z * b[j];
                acc[3][j] += a.w * b[j];
            }
        }
        __syncthreads();
    }

    // ---- epilogue: bias (+ BN + ReLU) ----
#pragma unroll
    for (int i = 0; i < 4; i++) {
        int m = m0 + tm * 4 + i;
        if (m >= N) continue;
        float vals[TN];
#pragma unroll
        for (int j = 0; j < TN; j++) {
            int n = tn * TN + j;
            float v = acc[i][j] + bias[n];
            if (BN_RELU) {
                float rs = rsqrtf(var[n] + BN_EPS);
                float scale = rs * g[n];
                v = v * scale + (bt[n] - mu[n] * scale);
                v = fmaxf(v, 0.f);
            }
            vals[j] = v;
        }
#pragma unroll
        for (int j4 = 0; j4 < TN / 4; j4++) {
            float4 v4 = make_float4(vals[j4 * 4 + 0], vals[j4 * 4 + 1],
                                    vals[j4 * 4 + 2], vals[j4 * 4 + 3]);
            *(float4*)&out[(size_t)m * NOUT + tn * TN + j4 * 4] = v4;
        }
    }
}

extern "C" void kernel_launch(void* const* d_in, const int* in_sizes, int n_in,
                              void* d_out, int out_size, void* d_ws, size_t ws_size,
                              hipStream_t stream) {
    const float* x     = (const float*)d_in[0];
    const int*   edge  = (const int*)d_in[1];
    const float* W1l   = (const float*)d_in[2];
    const float* b1    = (const float*)d_in[3];
    const float* W1r   = (const float*)d_in[4];
    const float* gamma = (const float*)d_in[5];
    const float* beta  = (const float*)d_in[6];
    const float* mean  = (const float*)d_in[7];
    const float* var   = (const float*)d_in[8];
    const float* W2l   = (const float*)d_in[9];
    const float* b2    = (const float*)d_in[10];
    const float* W2r   = (const float*)d_in[11];

    const int N = in_sizes[0] / FEAT;
    const int E = in_sizes[1] / 2;
    const int* srcI = edge;
    const int* dstI = edge + E;

    // workspace layout:
    // floats: agg[N*128] | h[N*128] | Wt1[32768] | Wt2[16384]
    // uints : degi[N] | row_start[N+1] | write_ptr[N] | partials[1024] | csr_src[E]
    float* agg = (float*)d_ws;
    float* h   = agg + (size_t)N * FEAT;
    float* Wt1 = h + (size_t)N * FEAT;
    float* Wt2 = Wt1 + 256 * 128;
    unsigned* degi      = (unsigned*)(Wt2 + 256 * 64);
    unsigned* row_start = degi + N;
    unsigned* write_ptr = row_start + (N + 1);
    unsigned* partials  = write_ptr + N;
    unsigned* csr_src   = partials + 1024;

    float* outp = (float*)d_out;

    const int nb = (N + 255) / 256;  // scan blocks (<=1024 for N<=262144)

    hipMemsetAsync(degi, 0, (size_t)N * sizeof(unsigned), stream);

    prep_weights<<<128, 256, 0, stream>>>(W1l, W1r, W2l, W2r, Wt1, Wt2);
    count_deg<<<(E + 255) / 256, 256, 0, stream>>>(dstI, E, degi);
    scan_block<<<nb, 256, 0, stream>>>(degi, row_start, partials, N);
    scan_partials<<<1, 1024, 0, stream>>>(partials, nb);
    scan_finish<<<nb, 256, 0, stream>>>(row_start, write_ptr, partials, N, E);
    fill_csr<<<(E + 255) / 256, 256, 0, stream>>>(srcI, dstI, E, write_ptr, csr_src);

    // layer 1: gather-mean + fused GEMM/BN/ReLU
    gather_mean<<<(N * 64 + 255) / 256, 256, 0, stream>>>(x, row_start, csr_src, agg, N);
    sage_layer<128, true><<<(N + 63) / 64, 256, 0, stream>>>(
        agg, x, Wt1, b1, gamma, beta, mean, var, h, N);

    // layer 2
    gather_mean<<<(N * 64 + 255) / 256, 256, 0, stream>>>(h, row_start, csr_src, agg, N);
    sage_layer<64, false><<<(N + 63) / 64, 256, 0, stream>>>(
        agg, h, Wt2, b2, gamma, beta, mean, var, outp, N);
}

// Round 3
// 634.057 us; speedup vs baseline: 9.0037x; 1.2637x over previous
//
#include <hip/hip_runtime.h>

#define FEAT 128
#define BN_EPS 1e-5f

// ---------------- weight prep ------------------------------------------------
// Wt1[k][n], k in [0,256), n in [0,128): k<128 -> W1l[n][k] (agg path), else W1r[n][k-128]
// Wc2[k][n], k in [0,128), n in [0,128): n<64 -> W2l[n][k] (u path), else W2r[n-64][k] (v path)
__global__ void prep_weights(const float* __restrict__ W1l, const float* __restrict__ W1r,
                             const float* __restrict__ W2l, const float* __restrict__ W2r,
                             float* __restrict__ Wt1, float* __restrict__ Wc2) {
    int tid = blockIdx.x * blockDim.x + threadIdx.x;
    if (tid < 256 * 128) {
        int k = tid >> 7, n = tid & 127;
        Wt1[tid] = (k < 128) ? W1l[n * 128 + k] : W1r[n * 128 + (k - 128)];
    }
    if (tid < 128 * 128) {
        int k = tid >> 7, n = tid & 127;
        Wc2[tid] = (n < 64) ? W2l[n * 128 + k] : W2r[(n - 64) * 128 + k];
    }
}

// ---------------- degree histogram (uint) -----------------------------------
__global__ void count_deg(const int* __restrict__ dst, int E, unsigned* __restrict__ degi) {
    int i = blockIdx.x * blockDim.x + threadIdx.x;
    if (i < E) atomicAdd(&degi[dst[i]], 1u);
}

// ---------------- hierarchical exclusive scan over degi ---------------------
__global__ void scan_block(const unsigned* __restrict__ degi, unsigned* __restrict__ excl,
                           unsigned* __restrict__ partials, int N) {
    __shared__ unsigned buf[256];
    int i = blockIdx.x * 256 + threadIdx.x;
    unsigned v = (i < N) ? degi[i] : 0u;
    buf[threadIdx.x] = v;
    __syncthreads();
    for (int off = 1; off < 256; off <<= 1) {
        unsigned t = (threadIdx.x >= (unsigned)off) ? buf[threadIdx.x - off] : 0u;
        __syncthreads();
        buf[threadIdx.x] += t;
        __syncthreads();
    }
    if (i < N) excl[i] = buf[threadIdx.x] - v;
    if (threadIdx.x == 255) partials[blockIdx.x] = buf[255];
}

__global__ void scan_partials(unsigned* __restrict__ partials, int nb) {
    __shared__ unsigned buf[1024];
    unsigned v = ((int)threadIdx.x < nb) ? partials[threadIdx.x] : 0u;
    buf[threadIdx.x] = v;
    __syncthreads();
    for (int off = 1; off < 1024; off <<= 1) {
        unsigned t = (threadIdx.x >= (unsigned)off) ? buf[threadIdx.x - off] : 0u;
        __syncthreads();
        buf[threadIdx.x] += t;
        __syncthreads();
    }
    if ((int)threadIdx.x < nb) partials[threadIdx.x] = buf[threadIdx.x] - v;
}

__global__ void scan_finish(unsigned* __restrict__ row_start, unsigned* __restrict__ write_ptr,
                            const unsigned* __restrict__ partials, int N, int E) {
    int i = blockIdx.x * blockDim.x + threadIdx.x;
    if (i < N) {
        unsigned r = row_start[i] + partials[i >> 8];
        row_start[i] = r;
        write_ptr[i] = r;
    }
    if (i == 0) row_start[N] = (unsigned)E;
}

// ---------------- CSR fill: one int atomic per edge -------------------------
__global__ void fill_csr(const int* __restrict__ src, const int* __restrict__ dst, int E,
                         unsigned* __restrict__ write_ptr, unsigned* __restrict__ csr_src) {
    int e = blockIdx.x * blockDim.x + threadIdx.x;
    if (e >= E) return;
    unsigned pos = atomicAdd(&write_ptr[dst[e]], 1u);
    csr_src[pos] = (unsigned)src[e];
}

// ---------------- gather + mean over 128 feats: 32 lanes/node, float4 -------
__global__ __launch_bounds__(256) void gather_mean_f128(const float* __restrict__ feat,
                                                        const unsigned* __restrict__ row_start,
                                                        const unsigned* __restrict__ csr_src,
                                                        float* __restrict__ agg, int N) {
    int gid = blockIdx.x * 256 + threadIdx.x;
    int node = gid >> 5;
    if (node >= N) return;
    int f = (threadIdx.x & 31) * 4;
    unsigned s0 = row_start[node], s1 = row_start[node + 1];
    float4 acc = make_float4(0.f, 0.f, 0.f, 0.f);
    unsigned i = s0;
    for (; i + 2 <= s1; i += 2) {
        unsigned a = csr_src[i], b = csr_src[i + 1];
        float4 va = *(const float4*)(feat + (size_t)a * 128 + f);
        float4 vb = *(const float4*)(feat + (size_t)b * 128 + f);
        acc.x += va.x + vb.x; acc.y += va.y + vb.y;
        acc.z += va.z + vb.z; acc.w += va.w + vb.w;
    }
    if (i < s1) {
        unsigned a = csr_src[i];
        float4 va = *(const float4*)(feat + (size_t)a * 128 + f);
        acc.x += va.x; acc.y += va.y; acc.z += va.z; acc.w += va.w;
    }
    float inv = (s1 > s0) ? 1.0f / (float)(s1 - s0) : 0.f;
    acc.x *= inv; acc.y *= inv; acc.z *= inv; acc.w *= inv;
    *(float4*)(agg + (size_t)node * 128 + f) = acc;
}

// ---------------- layer-2 finish: out = mean_agg(u) + v ---------------------
// uv rows: [u(64) | v(64)], 16 lanes/node, float4
__global__ __launch_bounds__(256) void gather_out_f64(const float* __restrict__ uv,
                                                      const unsigned* __restrict__ row_start,
                                                      const unsigned* __restrict__ csr_src,
                                                      float* __restrict__ out, int N) {
    int gid = blockIdx.x * 256 + threadIdx.x;
    int node = gid >> 4;
    if (node >= N) return;
    int f = (threadIdx.x & 15) * 4;
    unsigned s0 = row_start[node], s1 = row_start[node + 1];
    float4 acc = make_float4(0.f, 0.f, 0.f, 0.f);
    unsigned i = s0;
    for (; i + 2 <= s1; i += 2) {
        unsigned a = csr_src[i], b = csr_src[i + 1];
        float4 va = *(const float4*)(uv + (size_t)a * 128 + f);
        float4 vb = *(const float4*)(uv + (size_t)b * 128 + f);
        acc.x += va.x + vb.x; acc.y += va.y + vb.y;
        acc.z += va.z + vb.z; acc.w += va.w + vb.w;
    }
    if (i < s1) {
        unsigned a = csr_src[i];
        float4 va = *(const float4*)(uv + (size_t)a * 128 + f);
        acc.x += va.x; acc.y += va.y; acc.z += va.z; acc.w += va.w;
    }
    float inv = (s1 > s0) ? 1.0f / (float)(s1 - s0) : 0.f;
    float4 v = *(const float4*)(uv + (size_t)node * 128 + 64 + f);
    acc.x = acc.x * inv + v.x; acc.y = acc.y * inv + v.y;
    acc.z = acc.z * inv + v.z; acc.w = acc.w * inv + v.w;
    *(float4*)(out + (size_t)node * 64 + f) = acc;
}

// ---------------- layer 1: C[N,128] = [agg | x] @ Wt1 + bias, BN, ReLU ------
__global__ __launch_bounds__(256) void sage_layer1(
    const float* __restrict__ agg, const float* __restrict__ xin,
    const float* __restrict__ Wt, const float* __restrict__ bias,
    const float* __restrict__ g, const float* __restrict__ bt,
    const float* __restrict__ mu, const float* __restrict__ var,
    float* __restrict__ out, int N)
{
    constexpr int NOUT = 128;
    constexpr int TM = 64;
    constexpr int BK = 16;
    constexpr int TN = 8;

    __shared__ __align__(16) float As[BK][TM];
    __shared__ __align__(16) float Bs[BK * NOUT];

    const int tid = threadIdx.x;
    const int m0 = blockIdx.x * TM;
    const int tm = tid & 15;
    const int tn = tid >> 4;

    float acc[4][TN];
#pragma unroll
    for (int i = 0; i < 4; i++)
#pragma unroll
        for (int j = 0; j < TN; j++) acc[i][j] = 0.f;

    const int lm = tid >> 2;
    const int lk = (tid & 3) * 4;
    const int node = m0 + lm;
    const bool mvalid = node < N;

    for (int kc = 0; kc < 256; kc += BK) {
        float4 av = make_float4(0.f, 0.f, 0.f, 0.f);
        if (mvalid) {
            int k = kc + lk;
            if (k < 128) av = *(const float4*)&agg[(size_t)node * FEAT + k];
            else         av = *(const float4*)&xin[(size_t)node * FEAT + (k - 128)];
        }
        As[lk + 0][lm] = av.x;
        As[lk + 1][lm] = av.y;
        As[lk + 2][lm] = av.z;
        As[lk + 3][lm] = av.w;
        {
            const float4* src4 = (const float4*)(Wt + (size_t)kc * NOUT);
            float4* dst4 = (float4*)Bs;
#pragma unroll
            for (int r = 0; r < (BK * NOUT / 4) / 256; r++)
                dst4[tid + r * 256] = src4[tid + r * 256];
        }
        __syncthreads();
#pragma unroll
        for (int kk = 0; kk < BK; kk++) {
            float4 a = *(const float4*)&As[kk][tm * 4];
            float b[TN];
            const float4* brow = (const float4*)&Bs[kk * NOUT + tn * TN];
#pragma unroll
            for (int j4 = 0; j4 < TN / 4; j4++) {
                float4 t = brow[j4];
                b[j4 * 4 + 0] = t.x; b[j4 * 4 + 1] = t.y;
                b[j4 * 4 + 2] = t.z; b[j4 * 4 + 3] = t.w;
            }
#pragma unroll
            for (int j = 0; j < TN; j++) {
                acc[0][j] += a.x * b[j];
                acc[1][j] += a.y * b[j];
                acc[2][j] += a.z * b[j];
                acc[3][j] += a.w * b[j];
            }
        }
        __syncthreads();
    }

#pragma unroll
    for (int i = 0; i < 4; i++) {
        int m = m0 + tm * 4 + i;
        if (m >= N) continue;
        float vals[TN];
#pragma unroll
        for (int j = 0; j < TN; j++) {
            int n = tn * TN + j;
            float v = acc[i][j] + bias[n];
            float rs = rsqrtf(var[n] + BN_EPS);
            float scale = rs * g[n];
            v = v * scale + (bt[n] - mu[n] * scale);
            vals[j] = fmaxf(v, 0.f);
        }
#pragma unroll
        for (int j4 = 0; j4 < TN / 4; j4++) {
            float4 v4 = make_float4(vals[j4 * 4 + 0], vals[j4 * 4 + 1],
                                    vals[j4 * 4 + 2], vals[j4 * 4 + 3]);
            *(float4*)&out[(size_t)m * NOUT + tn * TN + j4 * 4] = v4;
        }
    }
}

// ---------------- layer 2 transform: uv[N,128] = h @ Wc2 (+b2 on v half) ----
__global__ __launch_bounds__(256) void gemm_uv(
    const float* __restrict__ h, const float* __restrict__ Wc,
    const float* __restrict__ b2, float* __restrict__ uv, int N)
{
    constexpr int NOUT = 128;
    constexpr int TM = 64;
    constexpr int BK = 16;
    constexpr int TN = 8;

    __shared__ __align__(16) float As[BK][TM];
    __shared__ __align__(16) float Bs[BK * NOUT];

    const int tid = threadIdx.x;
    const int m0 = blockIdx.x * TM;
    const int tm = tid & 15;
    const int tn = tid >> 4;

    float acc[4][TN];
#pragma unroll
    for (int i = 0; i < 4; i++)
#pragma unroll
        for (int j = 0; j < TN; j++) acc[i][j] = 0.f;

    const int lm = tid >> 2;
    const int lk = (tid & 3) * 4;
    const int node = m0 + lm;
    const bool mvalid = node < N;

    for (int kc = 0; kc < 128; kc += BK) {
        float4 av = make_float4(0.f, 0.f, 0.f, 0.f);
        if (mvalid) av = *(const float4*)&h[(size_t)node * FEAT + kc + lk];
        As[lk + 0][lm] = av.x;
        As[lk + 1][lm] = av.y;
        As[lk + 2][lm] = av.z;
        As[lk + 3][lm] = av.w;
        {
            const float4* src4 = (const float4*)(Wc + (size_t)kc * NOUT);
            float4* dst4 = (float4*)Bs;
#pragma unroll
            for (int r = 0; r < (BK * NOUT / 4) / 256; r++)
                dst4[tid + r * 256] = src4[tid + r * 256];
        }
        __syncthreads();
#pragma unroll
        for (int kk = 0; kk < BK; kk++) {
            float4 a = *(const float4*)&As[kk][tm * 4];
            float b[TN];
            const float4* brow = (const float4*)&Bs[kk * NOUT + tn * TN];
#pragma unroll
            for (int j4 = 0; j4 < TN / 4; j4++) {
                float4 t = brow[j4];
                b[j4 * 4 + 0] = t.x; b[j4 * 4 + 1] = t.y;
                b[j4 * 4 + 2] = t.z; b[j4 * 4 + 3] = t.w;
            }
#pragma unroll
            for (int j = 0; j < TN; j++) {
                acc[0][j] += a.x * b[j];
                acc[1][j] += a.y * b[j];
                acc[2][j] += a.z * b[j];
                acc[3][j] += a.w * b[j];
            }
        }
        __syncthreads();
    }

    // bias only on v half (n >= 64); per-thread n-range is uniform in tn
#pragma unroll
    for (int i = 0; i < 4; i++) {
        int m = m0 + tm * 4 + i;
        if (m >= N) continue;
        float vals[TN];
#pragma unroll
        for (int j = 0; j < TN; j++) {
            int n = tn * TN + j;
            vals[j] = acc[i][j] + ((n >= 64) ? b2[n - 64] : 0.f);
        }
#pragma unroll
        for (int j4 = 0; j4 < TN / 4; j4++) {
            float4 v4 = make_float4(vals[j4 * 4 + 0], vals[j4 * 4 + 1],
                                    vals[j4 * 4 + 2], vals[j4 * 4 + 3]);
            *(float4*)&uv[(size_t)m * NOUT + tn * TN + j4 * 4] = v4;
        }
    }
}

extern "C" void kernel_launch(void* const* d_in, const int* in_sizes, int n_in,
                              void* d_out, int out_size, void* d_ws, size_t ws_size,
                              hipStream_t stream) {
    const float* x     = (const float*)d_in[0];
    const int*   edge  = (const int*)d_in[1];
    const float* W1l   = (const float*)d_in[2];
    const float* b1    = (const float*)d_in[3];
    const float* W1r   = (const float*)d_in[4];
    const float* gamma = (const float*)d_in[5];
    const float* beta  = (const float*)d_in[6];
    const float* mean  = (const float*)d_in[7];
    const float* var   = (const float*)d_in[8];
    const float* W2l   = (const float*)d_in[9];
    const float* b2    = (const float*)d_in[10];
    const float* W2r   = (const float*)d_in[11];

    const int N = in_sizes[0] / FEAT;
    const int E = in_sizes[1] / 2;
    const int* srcI = edge;
    const int* dstI = edge + E;

    // ws layout:
    // floats: agg/uv[N*128] | h[N*128] | Wt1[32768] | Wc2[16384]
    // uints : degi[N] | row_start[N+1] | write_ptr[N] | partials[1024] | csr_src[E]
    float* agg = (float*)d_ws;          // reused as uv for layer 2
    float* h   = agg + (size_t)N * FEAT;
    float* Wt1 = h + (size_t)N * FEAT;
    float* Wc2 = Wt1 + 256 * 128;
    unsigned* degi      = (unsigned*)(Wc2 + 128 * 128);
    unsigned* row_start = degi + N;
    unsigned* write_ptr = row_start + (N + 1);
    unsigned* partials  = write_ptr + N;
    unsigned* csr_src   = partials + 1024;

    float* outp = (float*)d_out;
    const int nb = (N + 255) / 256;

    hipMemsetAsync(degi, 0, (size_t)N * sizeof(unsigned), stream);

    prep_weights<<<128, 256, 0, stream>>>(W1l, W1r, W2l, W2r, Wt1, Wc2);
    count_deg<<<(E + 255) / 256, 256, 0, stream>>>(dstI, E, degi);
    scan_block<<<nb, 256, 0, stream>>>(degi, row_start, partials, N);
    scan_partials<<<1, 1024, 0, stream>>>(partials, nb);
    scan_finish<<<nb, 256, 0, stream>>>(row_start, write_ptr, partials, N, E);
    fill_csr<<<(E + 255) / 256, 256, 0, stream>>>(srcI, dstI, E, write_ptr, csr_src);

    // layer 1: gather-mean(x) -> agg; fused GEMM+BN+ReLU -> h
    gather_mean_f128<<<(N * 32 + 255) / 256, 256, 0, stream>>>(x, row_start, csr_src, agg, N);
    sage_layer1<<<(N + 63) / 64, 256, 0, stream>>>(
        agg, x, Wt1, b1, gamma, beta, mean, var, h, N);

    // layer 2: transform first (u|v), then gather-mean(u)+v -> out
    gemm_uv<<<(N + 63) / 64, 256, 0, stream>>>(h, Wc2, b2, agg, N);
    gather_out_f64<<<(N * 16 + 255) / 256, 256, 0, stream>>>(agg, row_start, csr_src, outp, N);
}

// Round 4
// 545.903 us; speedup vs baseline: 10.4576x; 1.1615x over previous
//
#include <hip/hip_runtime.h>

#define FEAT 128
#define BN_EPS 1e-5f
#define CSTRIDE 16   // one degree counter per 64B line

// ---------------- weight prep ------------------------------------------------
// Wt1[k][n], k in [0,256), n in [0,128): k<128 -> W1l[n][k] (agg path), else W1r[n][k-128]
// Wc2[k][n], k in [0,128), n in [0,128): n<64 -> W2l[n][k] (u path), else W2r[n-64][k] (v path)
__global__ void prep_weights(const float* __restrict__ W1l, const float* __restrict__ W1r,
                             const float* __restrict__ W2l, const float* __restrict__ W2r,
                             float* __restrict__ Wt1, float* __restrict__ Wc2) {
    int tid = blockIdx.x * blockDim.x + threadIdx.x;
    if (tid < 256 * 128) {
        int k = tid >> 7, n = tid & 127;
        Wt1[tid] = (k < 128) ? W1l[n * 128 + k] : W1r[n * 128 + (k - 128)];
    }
    if (tid < 128 * 128) {
        int k = tid >> 7, n = tid & 127;
        Wc2[tid] = (n < 64) ? W2l[n * 128 + k] : W2r[(n - 64) * 128 + k];
    }
}

// ---------------- fused degree count + per-edge rank -------------------------
// degc is padded: counter for node i lives at degc[i*CSTRIDE]
__global__ void count_rank(const int* __restrict__ dst, int E,
                           unsigned* __restrict__ degc, unsigned* __restrict__ rank) {
    int e = blockIdx.x * blockDim.x + threadIdx.x;
    if (e >= E) return;
    unsigned r = atomicAdd(&degc[(size_t)dst[e] * CSTRIDE], 1u);
    rank[e] = r;
}

// ---------------- hierarchical exclusive scan over padded degc ---------------
__global__ void scan_block(const unsigned* __restrict__ degc, unsigned* __restrict__ excl,
                           unsigned* __restrict__ partials, int N) {
    __shared__ unsigned buf[256];
    int i = blockIdx.x * 256 + threadIdx.x;
    unsigned v = (i < N) ? degc[(size_t)i * CSTRIDE] : 0u;
    buf[threadIdx.x] = v;
    __syncthreads();
    for (int off = 1; off < 256; off <<= 1) {
        unsigned t = (threadIdx.x >= (unsigned)off) ? buf[threadIdx.x - off] : 0u;
        __syncthreads();
        buf[threadIdx.x] += t;
        __syncthreads();
    }
    if (i < N) excl[i] = buf[threadIdx.x] - v;
    if (threadIdx.x == 255) partials[blockIdx.x] = buf[255];
}

__global__ void scan_partials(unsigned* __restrict__ partials, int nb) {
    __shared__ unsigned buf[1024];
    unsigned v = ((int)threadIdx.x < nb) ? partials[threadIdx.x] : 0u;
    buf[threadIdx.x] = v;
    __syncthreads();
    for (int off = 1; off < 1024; off <<= 1) {
        unsigned t = (threadIdx.x >= (unsigned)off) ? buf[threadIdx.x - off] : 0u;
        __syncthreads();
        buf[threadIdx.x] += t;
        __syncthreads();
    }
    if ((int)threadIdx.x < nb) partials[threadIdx.x] = buf[threadIdx.x] - v;
}

__global__ void scan_finish(unsigned* __restrict__ row_start,
                            const unsigned* __restrict__ partials, int N, int E) {
    int i = blockIdx.x * blockDim.x + threadIdx.x;
    if (i < N) row_start[i] = row_start[i] + partials[i >> 8];
    if (i == 0) row_start[N] = (unsigned)E;
}

// ---------------- CSR fill: NO atomics (pos = row_start[d] + rank[e]) --------
__global__ void fill_csr(const int* __restrict__ src, const int* __restrict__ dst, int E,
                         const unsigned* __restrict__ row_start,
                         const unsigned* __restrict__ rank,
                         unsigned* __restrict__ csr_src) {
    int e = blockIdx.x * blockDim.x + threadIdx.x;
    if (e >= E) return;
    unsigned pos = row_start[dst[e]] + rank[e];
    csr_src[pos] = (unsigned)src[e];
}

// ---------------- gather + mean over 128 feats: 32 lanes/node, float4 -------
__global__ __launch_bounds__(256) void gather_mean_f128(const float* __restrict__ feat,
                                                        const unsigned* __restrict__ row_start,
                                                        const unsigned* __restrict__ csr_src,
                                                        float* __restrict__ agg, int N) {
    int gid = blockIdx.x * 256 + threadIdx.x;
    int node = gid >> 5;
    if (node >= N) return;
    int f = (threadIdx.x & 31) * 4;
    unsigned s0 = row_start[node], s1 = row_start[node + 1];
    float4 acc = make_float4(0.f, 0.f, 0.f, 0.f);
    unsigned i = s0;
    for (; i + 2 <= s1; i += 2) {
        unsigned a = csr_src[i], b = csr_src[i + 1];
        float4 va = *(const float4*)(feat + (size_t)a * 128 + f);
        float4 vb = *(const float4*)(feat + (size_t)b * 128 + f);
        acc.x += va.x + vb.x; acc.y += va.y + vb.y;
        acc.z += va.z + vb.z; acc.w += va.w + vb.w;
    }
    if (i < s1) {
        unsigned a = csr_src[i];
        float4 va = *(const float4*)(feat + (size_t)a * 128 + f);
        acc.x += va.x; acc.y += va.y; acc.z += va.z; acc.w += va.w;
    }
    float inv = (s1 > s0) ? 1.0f / (float)(s1 - s0) : 0.f;
    acc.x *= inv; acc.y *= inv; acc.z *= inv; acc.w *= inv;
    *(float4*)(agg + (size_t)node * 128 + f) = acc;
}

// ---------------- layer-2 finish: out = mean_agg(u) + v ---------------------
// uv rows: [u(64) | v(64)], 16 lanes/node, float4
__global__ __launch_bounds__(256) void gather_out_f64(const float* __restrict__ uv,
                                                      const unsigned* __restrict__ row_start,
                                                      const unsigned* __restrict__ csr_src,
                                                      float* __restrict__ out, int N) {
    int gid = blockIdx.x * 256 + threadIdx.x;
    int node = gid >> 4;
    if (node >= N) return;
    int f = (threadIdx.x & 15) * 4;
    unsigned s0 = row_start[node], s1 = row_start[node + 1];
    float4 acc = make_float4(0.f, 0.f, 0.f, 0.f);
    unsigned i = s0;
    for (; i + 2 <= s1; i += 2) {
        unsigned a = csr_src[i], b = csr_src[i + 1];
        float4 va = *(const float4*)(uv + (size_t)a * 128 + f);
        float4 vb = *(const float4*)(uv + (size_t)b * 128 + f);
        acc.x += va.x + vb.x; acc.y += va.y + vb.y;
        acc.z += va.z + vb.z; acc.w += va.w + vb.w;
    }
    if (i < s1) {
        unsigned a = csr_src[i];
        float4 va = *(const float4*)(uv + (size_t)a * 128 + f);
        acc.x += va.x; acc.y += va.y; acc.z += va.z; acc.w += va.w;
    }
    float inv = (s1 > s0) ? 1.0f / (float)(s1 - s0) : 0.f;
    float4 v = *(const float4*)(uv + (size_t)node * 128 + 64 + f);
    acc.x = acc.x * inv + v.x; acc.y = acc.y * inv + v.y;
    acc.z = acc.z * inv + v.z; acc.w = acc.w * inv + v.w;
    *(float4*)(out + (size_t)node * 64 + f) = acc;
}

// ---------------- layer 1: C[N,128] = [agg | x] @ Wt1 + bias, BN, ReLU ------
__global__ __launch_bounds__(256) void sage_layer1(
    const float* __restrict__ agg, const float* __restrict__ xin,
    const float* __restrict__ Wt, const float* __restrict__ bias,
    const float* __restrict__ g, const float* __restrict__ bt,
    const float* __restrict__ mu, const float* __restrict__ var,
    float* __restrict__ out, int N)
{
    constexpr int NOUT = 128;
    constexpr int TM = 64;
    constexpr int BK = 16;
    constexpr int TN = 8;

    __shared__ __align__(16) float As[BK][TM];
    __shared__ __align__(16) float Bs[BK * NOUT];

    const int tid = threadIdx.x;
    const int m0 = blockIdx.x * TM;
    const int tm = tid & 15;
    const int tn = tid >> 4;

    float acc[4][TN];
#pragma unroll
    for (int i = 0; i < 4; i++)
#pragma unroll
        for (int j = 0; j < TN; j++) acc[i][j] = 0.f;

    const int lm = tid >> 2;
    const int lk = (tid & 3) * 4;
    const int node = m0 + lm;
    const bool mvalid = node < N;

    for (int kc = 0; kc < 256; kc += BK) {
        float4 av = make_float4(0.f, 0.f, 0.f, 0.f);
        if (mvalid) {
            int k = kc + lk;
            if (k < 128) av = *(const float4*)&agg[(size_t)node * FEAT + k];
            else         av = *(const float4*)&xin[(size_t)node * FEAT + (k - 128)];
        }
        As[lk + 0][lm] = av.x;
        As[lk + 1][lm] = av.y;
        As[lk + 2][lm] = av.z;
        As[lk + 3][lm] = av.w;
        {
            const float4* src4 = (const float4*)(Wt + (size_t)kc * NOUT);
            float4* dst4 = (float4*)Bs;
#pragma unroll
            for (int r = 0; r < (BK * NOUT / 4) / 256; r++)
                dst4[tid + r * 256] = src4[tid + r * 256];
        }
        __syncthreads();
#pragma unroll
        for (int kk = 0; kk < BK; kk++) {
            float4 a = *(const float4*)&As[kk][tm * 4];
            float b[TN];
            const float4* brow = (const float4*)&Bs[kk * NOUT + tn * TN];
#pragma unroll
            for (int j4 = 0; j4 < TN / 4; j4++) {
                float4 t = brow[j4];
                b[j4 * 4 + 0] = t.x; b[j4 * 4 + 1] = t.y;
                b[j4 * 4 + 2] = t.z; b[j4 * 4 + 3] = t.w;
            }
#pragma unroll
            for (int j = 0; j < TN; j++) {
                acc[0][j] += a.x * b[j];
                acc[1][j] += a.y * b[j];
                acc[2][j] += a.z * b[j];
                acc[3][j] += a.w * b[j];
            }
        }
        __syncthreads();
    }

#pragma unroll
    for (int i = 0; i < 4; i++) {
        int m = m0 + tm * 4 + i;
        if (m >= N) continue;
        float vals[TN];
#pragma unroll
        for (int j = 0; j < TN; j++) {
            int n = tn * TN + j;
            float v = acc[i][j] + bias[n];
            float rs = rsqrtf(var[n] + BN_EPS);
            float scale = rs * g[n];
            v = v * scale + (bt[n] - mu[n] * scale);
            vals[j] = fmaxf(v, 0.f);
        }
#pragma unroll
        for (int j4 = 0; j4 < TN / 4; j4++) {
            float4 v4 = make_float4(vals[j4 * 4 + 0], vals[j4 * 4 + 1],
                                    vals[j4 * 4 + 2], vals[j4 * 4 + 3]);
            *(float4*)&out[(size_t)m * NOUT + tn * TN + j4 * 4] = v4;
        }
    }
}

// ---------------- layer 2 transform: uv[N,128] = h @ Wc2 (+b2 on v half) ----
__global__ __launch_bounds__(256) void gemm_uv(
    const float* __restrict__ h, const float* __restrict__ Wc,
    const float* __restrict__ b2, float* __restrict__ uv, int N)
{
    constexpr int NOUT = 128;
    constexpr int TM = 64;
    constexpr int BK = 16;
    constexpr int TN = 8;

    __shared__ __align__(16) float As[BK][TM];
    __shared__ __align__(16) float Bs[BK * NOUT];

    const int tid = threadIdx.x;
    const int m0 = blockIdx.x * TM;
    const int tm = tid & 15;
    const int tn = tid >> 4;

    float acc[4][TN];
#pragma unroll
    for (int i = 0; i < 4; i++)
#pragma unroll
        for (int j = 0; j < TN; j++) acc[i][j] = 0.f;

    const int lm = tid >> 2;
    const int lk = (tid & 3) * 4;
    const int node = m0 + lm;
    const bool mvalid = node < N;

    for (int kc = 0; kc < 128; kc += BK) {
        float4 av = make_float4(0.f, 0.f, 0.f, 0.f);
        if (mvalid) av = *(const float4*)&h[(size_t)node * FEAT + kc + lk];
        As[lk + 0][lm] = av.x;
        As[lk + 1][lm] = av.y;
        As[lk + 2][lm] = av.z;
        As[lk + 3][lm] = av.w;
        {
            const float4* src4 = (const float4*)(Wc + (size_t)kc * NOUT);
            float4* dst4 = (float4*)Bs;
#pragma unroll
            for (int r = 0; r < (BK * NOUT / 4) / 256; r++)
                dst4[tid + r * 256] = src4[tid + r * 256];
        }
        __syncthreads();
#pragma unroll
        for (int kk = 0; kk < BK; kk++) {
            float4 a = *(const float4*)&As[kk][tm * 4];
            float b[TN];
            const float4* brow = (const float4*)&Bs[kk * NOUT + tn * TN];
#pragma unroll
            for (int j4 = 0; j4 < TN / 4; j4++) {
                float4 t = brow[j4];
                b[j4 * 4 + 0] = t.x; b[j4 * 4 + 1] = t.y;
                b[j4 * 4 + 2] = t.z; b[j4 * 4 + 3] = t.w;
            }
#pragma unroll
            for (int j = 0; j < TN; j++) {
                acc[0][j] += a.x * b[j];
                acc[1][j] += a.y * b[j];
                acc[2][j] += a.z * b[j];
                acc[3][j] += a.w * b[j];
            }
        }
        __syncthreads();
    }

#pragma unroll
    for (int i = 0; i < 4; i++) {
        int m = m0 + tm * 4 + i;
        if (m >= N) continue;
        float vals[TN];
#pragma unroll
        for (int j = 0; j < TN; j++) {
            int n = tn * TN + j;
            vals[j] = acc[i][j] + ((n >= 64) ? b2[n - 64] : 0.f);
        }
#pragma unroll
        for (int j4 = 0; j4 < TN / 4; j4++) {
            float4 v4 = make_float4(vals[j4 * 4 + 0], vals[j4 * 4 + 1],
                                    vals[j4 * 4 + 2], vals[j4 * 4 + 3]);
            *(float4*)&uv[(size_t)m * NOUT + tn * TN + j4 * 4] = v4;
        }
    }
}

extern "C" void kernel_launch(void* const* d_in, const int* in_sizes, int n_in,
                              void* d_out, int out_size, void* d_ws, size_t ws_size,
                              hipStream_t stream) {
    const float* x     = (const float*)d_in[0];
    const int*   edge  = (const int*)d_in[1];
    const float* W1l   = (const float*)d_in[2];
    const float* b1    = (const float*)d_in[3];
    const float* W1r   = (const float*)d_in[4];
    const float* gamma = (const float*)d_in[5];
    const float* beta  = (const float*)d_in[6];
    const float* mean  = (const float*)d_in[7];
    const float* var   = (const float*)d_in[8];
    const float* W2l   = (const float*)d_in[9];
    const float* b2    = (const float*)d_in[10];
    const float* W2r   = (const float*)d_in[11];

    const int N = in_sizes[0] / FEAT;
    const int E = in_sizes[1] / 2;
    const int* srcI = edge;
    const int* dstI = edge + E;

    // ws layout:
    // floats: agg/uv[N*128] | h[N*128] | Wt1[32768] | Wc2[16384]
    // uints : degc[N*CSTRIDE] | row_start[N+1] | rank[E] | partials[1024] | csr_src[E]
    float* agg = (float*)d_ws;          // reused as uv for layer 2
    float* h   = agg + (size_t)N * FEAT;
    float* Wt1 = h + (size_t)N * FEAT;
    float* Wc2 = Wt1 + 256 * 128;
    unsigned* degc      = (unsigned*)(Wc2 + 128 * 128);
    unsigned* row_start = degc + (size_t)N * CSTRIDE;
    unsigned* rank      = row_start + (N + 1);
    unsigned* partials  = rank + E;
    unsigned* csr_src   = partials + 1024;

    float* outp = (float*)d_out;
    const int nb = (N + 255) / 256;

    hipMemsetAsync(degc, 0, (size_t)N * CSTRIDE * sizeof(unsigned), stream);

    prep_weights<<<128, 256, 0, stream>>>(W1l, W1r, W2l, W2r, Wt1, Wc2);
    count_rank<<<(E + 255) / 256, 256, 0, stream>>>(dstI, E, degc, rank);
    scan_block<<<nb, 256, 0, stream>>>(degc, row_start, partials, N);
    scan_partials<<<1, 1024, 0, stream>>>(partials, nb);
    scan_finish<<<nb, 256, 0, stream>>>(row_start, partials, N, E);
    fill_csr<<<(E + 255) / 256, 256, 0, stream>>>(srcI, dstI, E, row_start, rank, csr_src);

    // layer 1: gather-mean(x) -> agg; fused GEMM+BN+ReLU -> h
    gather_mean_f128<<<(N * 32 + 255) / 256, 256, 0, stream>>>(x, row_start, csr_src, agg, N);
    sage_layer1<<<(N + 63) / 64, 256, 0, stream>>>(
        agg, x, Wt1, b1, gamma, beta, mean, var, h, N);

    // layer 2: transform first (u|v), then gather-mean(u)+v -> out
    gemm_uv<<<(N + 63) / 64, 256, 0, stream>>>(h, Wc2, b2, agg, N);
    gather_out_f64<<<(N * 16 + 255) / 256, 256, 0, stream>>>(agg, row_start, csr_src, outp, N);
}

// Round 5
// 423.355 us; speedup vs baseline: 13.4848x; 1.2895x over previous
//
#include <hip/hip_runtime.h>

#define FEAT 128
#define BN_EPS 1e-5f
#define CSTRIDE 16   // one degree counter per 64B line

typedef __attribute__((ext_vector_type(8))) short s8frag;
typedef __attribute__((ext_vector_type(4))) float f4frag;

union FragU { uint4 u; s8frag v; };

__device__ __forceinline__ unsigned short f2bf(float f) {
    unsigned u = __float_as_uint(f);
    unsigned r = (u + 0x7fffu + ((u >> 16) & 1u)) >> 16;
    return (unsigned short)r;
}
__device__ __forceinline__ void unpack2(unsigned d, float& lo, float& hi) {
    lo = __uint_as_float(d << 16);
    hi = __uint_as_float(d & 0xffff0000u);
}

// ---------------- prep: bf16 weights + BN constants --------------------------
// Wb1[n][k] n<128,k<256: k<128 -> W1l[n][k], else W1r[n][k-128]
// Wb2[n][k] n<128,k<128: n<64 -> W2l[n][k],  else W2r[n-64][k]
// bnsc[n]=rsqrt(var+eps)*gamma; bnsh[n]=bnsc*(b1[n]-mu[n])+beta; cb2[n]=n<64?0:b2[n-64]
__global__ void prep_all(const float* __restrict__ W1l, const float* __restrict__ W1r,
                         const float* __restrict__ W2l, const float* __restrict__ W2r,
                         const float* __restrict__ b1, const float* __restrict__ g,
                         const float* __restrict__ bt, const float* __restrict__ mu,
                         const float* __restrict__ var, const float* __restrict__ b2,
                         unsigned short* __restrict__ Wb1, unsigned short* __restrict__ Wb2,
                         float* __restrict__ bnsc, float* __restrict__ bnsh,
                         float* __restrict__ cb2) {
    int tid = blockIdx.x * blockDim.x + threadIdx.x;
    if (tid < 128 * 256) {
        int n = tid >> 8, k = tid & 255;
        float w = (k < 128) ? W1l[n * 128 + k] : W1r[n * 128 + (k - 128)];
        Wb1[tid] = f2bf(w);
    }
    if (tid < 128 * 128) {
        int n = tid >> 7, k = tid & 127;
        float w = (n < 64) ? W2l[n * 128 + k] : W2r[(n - 64) * 128 + k];
        Wb2[tid] = f2bf(w);
    }
    if (tid < 128) {
        float sc = rsqrtf(var[tid] + BN_EPS) * g[tid];
        bnsc[tid] = sc;
        bnsh[tid] = sc * (b1[tid] - mu[tid]) + bt[tid];
        cb2[tid] = (tid < 64) ? 0.f : b2[tid - 64];
    }
}

// ---------------- x -> bf16 (8 elems/thread) ---------------------------------
__global__ void convert_x(const float* __restrict__ x, unsigned short* __restrict__ xb,
                          long long total8) {
    long long t = (long long)blockIdx.x * blockDim.x + threadIdx.x;
    if (t >= total8) return;
    const float4* src = (const float4*)(x) + t * 2;
    float4 a = src[0], b = src[1];
    uint4 o;
    o.x = f2bf(a.x) | ((unsigned)f2bf(a.y) << 16);
    o.y = f2bf(a.z) | ((unsigned)f2bf(a.w) << 16);
    o.z = f2bf(b.x) | ((unsigned)f2bf(b.y) << 16);
    o.w = f2bf(b.z) | ((unsigned)f2bf(b.w) << 16);
    ((uint4*)xb)[t] = o;
}

// ---------------- fused degree count + per-edge rank -------------------------
__global__ void count_rank(const int* __restrict__ dst, int E,
                           unsigned* __restrict__ degc, unsigned* __restrict__ rank) {
    int e = blockIdx.x * blockDim.x + threadIdx.x;
    if (e >= E) return;
    rank[e] = atomicAdd(&degc[(size_t)dst[e] * CSTRIDE], 1u);
}

// ---------------- hierarchical exclusive scan over padded degc ---------------
__global__ void scan_block(const unsigned* __restrict__ degc, unsigned* __restrict__ excl,
                           unsigned* __restrict__ partials, int N) {
    __shared__ unsigned buf[256];
    int i = blockIdx.x * 256 + threadIdx.x;
    unsigned v = (i < N) ? degc[(size_t)i * CSTRIDE] : 0u;
    buf[threadIdx.x] = v;
    __syncthreads();
    for (int off = 1; off < 256; off <<= 1) {
        unsigned t = (threadIdx.x >= (unsigned)off) ? buf[threadIdx.x - off] : 0u;
        __syncthreads();
        buf[threadIdx.x] += t;
        __syncthreads();
    }
    if (i < N) excl[i] = buf[threadIdx.x] - v;
    if (threadIdx.x == 255) partials[blockIdx.x] = buf[255];
}

__global__ void scan_partials(unsigned* __restrict__ partials, int nb) {
    __shared__ unsigned buf[1024];
    unsigned v = ((int)threadIdx.x < nb) ? partials[threadIdx.x] : 0u;
    buf[threadIdx.x] = v;
    __syncthreads();
    for (int off = 1; off < 1024; off <<= 1) {
        unsigned t = (threadIdx.x >= (unsigned)off) ? buf[threadIdx.x - off] : 0u;
        __syncthreads();
        buf[threadIdx.x] += t;
        __syncthreads();
    }
    if ((int)threadIdx.x < nb) partials[threadIdx.x] = buf[threadIdx.x] - v;
}

__global__ void scan_finish(unsigned* __restrict__ row_start,
                            const unsigned* __restrict__ partials, int N, int E) {
    int i = blockIdx.x * blockDim.x + threadIdx.x;
    if (i < N) row_start[i] = row_start[i] + partials[i >> 8];
    if (i == 0) row_start[N] = (unsigned)E;
}

// ---------------- CSR fill: atomic-free --------------------------------------
__global__ void fill_csr(const int* __restrict__ src, const int* __restrict__ dst, int E,
                         const unsigned* __restrict__ row_start,
                         const unsigned* __restrict__ rank,
                         unsigned* __restrict__ csr_src) {
    int e = blockIdx.x * blockDim.x + threadIdx.x;
    if (e >= E) return;
    csr_src[row_start[dst[e]] + rank[e]] = (unsigned)src[e];
}

// ---------------- gather + mean over 128 bf16 feats: 16 lanes/node -----------
__global__ __launch_bounds__(256) void gather_mean_bf(const unsigned short* __restrict__ xb,
                                                      const unsigned* __restrict__ row_start,
                                                      const unsigned* __restrict__ csr_src,
                                                      unsigned short* __restrict__ aggb, int N) {
    int gid = blockIdx.x * 256 + threadIdx.x;
    int node = gid >> 4;
    if (node >= N) return;
    int f = (threadIdx.x & 15) * 8;  // bf16 elem offset
    unsigned s0 = row_start[node], s1 = row_start[node + 1];
    float acc[8];
#pragma unroll
    for (int i = 0; i < 8; i++) acc[i] = 0.f;
    unsigned i = s0;
    for (; i + 2 <= s1; i += 2) {
        unsigned sa = csr_src[i], sb = csr_src[i + 1];
        uint4 da = *(const uint4*)(xb + (size_t)sa * 128 + f);
        uint4 db = *(const uint4*)(xb + (size_t)sb * 128 + f);
        float l, h;
        unpack2(da.x, l, h); acc[0] += l; acc[1] += h;
        unpack2(da.y, l, h); acc[2] += l; acc[3] += h;
        unpack2(da.z, l, h); acc[4] += l; acc[5] += h;
        unpack2(da.w, l, h); acc[6] += l; acc[7] += h;
        unpack2(db.x, l, h); acc[0] += l; acc[1] += h;
        unpack2(db.y, l, h); acc[2] += l; acc[3] += h;
        unpack2(db.z, l, h); acc[4] += l; acc[5] += h;
        unpack2(db.w, l, h); acc[6] += l; acc[7] += h;
    }
    if (i < s1) {
        unsigned sa = csr_src[i];
        uint4 da = *(const uint4*)(xb + (size_t)sa * 128 + f);
        float l, h;
        unpack2(da.x, l, h); acc[0] += l; acc[1] += h;
        unpack2(da.y, l, h); acc[2] += l; acc[3] += h;
        unpack2(da.z, l, h); acc[4] += l; acc[5] += h;
        unpack2(da.w, l, h); acc[6] += l; acc[7] += h;
    }
    float inv = (s1 > s0) ? 1.0f / (float)(s1 - s0) : 0.f;
    uint4 o;
    o.x = f2bf(acc[0] * inv) | ((unsigned)f2bf(acc[1] * inv) << 16);
    o.y = f2bf(acc[2] * inv) | ((unsigned)f2bf(acc[3] * inv) << 16);
    o.z = f2bf(acc[4] * inv) | ((unsigned)f2bf(acc[5] * inv) << 16);
    o.w = f2bf(acc[6] * inv) | ((unsigned)f2bf(acc[7] * inv) << 16);
    *(uint4*)(aggb + (size_t)node * 128 + f) = o;
}

// ---------------- layer 1 MFMA: h = BN(ReLU)([aggb|xb] @ Wb1^T) -> bf16 ------
// 4 waves/block, wave owns 16 rows x 128 cols. K=256, step 32.
__global__ __launch_bounds__(256) void sage1_mfma(
    const unsigned short* __restrict__ aggb, const unsigned short* __restrict__ xb,
    const unsigned short* __restrict__ Wb,   // [128][256]
    const float* __restrict__ bnsc, const float* __restrict__ bnsh,
    unsigned short* __restrict__ hb, int N)
{
    const int wave = threadIdx.x >> 6;
    const int lane = threadIdx.x & 63;
    const int mr = lane & 15;
    const int q = lane >> 4;
    const int m0 = blockIdx.x * 64 + wave * 16;
    const int m = m0 + mr;
    const bool mv = m < N;

    f4frag acc[8];
#pragma unroll
    for (int j = 0; j < 8; j++)
#pragma unroll
        for (int r = 0; r < 4; r++) acc[j][r] = 0.f;

#pragma unroll
    for (int kc = 0; kc < 256; kc += 32) {
        int k = kc + q * 8;
        FragU a;
        a.u = make_uint4(0u, 0u, 0u, 0u);
        if (mv) {
            const unsigned short* asrc = (kc < 128)
                ? (aggb + (size_t)m * 128 + k)
                : (xb + (size_t)m * 128 + (k - 128));
            a.u = *(const uint4*)asrc;
        }
#pragma unroll
        for (int j = 0; j < 8; j++) {
            FragU b;
            b.u = *(const uint4*)(Wb + (size_t)(j * 16 + mr) * 256 + k);
            acc[j] = __builtin_amdgcn_mfma_f32_16x16x32_bf16(a.v, b.v, acc[j], 0, 0, 0);
        }
    }

    // epilogue: C col = lane&15, row = q*4+r
    const int rowq = q * 4;
#pragma unroll
    for (int r = 0; r < 4; r++) {
        int mrow = m0 + rowq + r;
        if (mrow >= N) continue;
#pragma unroll
        for (int j = 0; j < 8; j++) {
            int n = j * 16 + mr;
            float v = acc[j][r] * bnsc[n] + bnsh[n];
            v = fmaxf(v, 0.f);
            hb[(size_t)mrow * 128 + n] = f2bf(v);
        }
    }
}

// ---------------- layer 2 MFMA: uv = hb @ Wb2^T (+cb2) -> bf16 ---------------
__global__ __launch_bounds__(256) void gemm_uv_mfma(
    const unsigned short* __restrict__ hb, const unsigned short* __restrict__ Wb,  // [128][128]
    const float* __restrict__ cb2, unsigned short* __restrict__ uvb, int N)
{
    const int wave = threadIdx.x >> 6;
    const int lane = threadIdx.x & 63;
    const int mr = lane & 15;
    const int q = lane >> 4;
    const int m0 = blockIdx.x * 64 + wave * 16;
    const int m = m0 + mr;
    const bool mv = m < N;

    f4frag acc[8];
#pragma unroll
    for (int j = 0; j < 8; j++)
#pragma unroll
        for (int r = 0; r < 4; r++) acc[j][r] = 0.f;

#pragma unroll
    for (int kc = 0; kc < 128; kc += 32) {
        int k = kc + q * 8;
        FragU a;
        a.u = make_uint4(0u, 0u, 0u, 0u);
        if (mv) a.u = *(const uint4*)(hb + (size_t)m * 128 + k);
#pragma unroll
        for (int j = 0; j < 8; j++) {
            FragU b;
            b.u = *(const uint4*)(Wb + (size_t)(j * 16 + mr) * 128 + k);
            acc[j] = __builtin_amdgcn_mfma_f32_16x16x32_bf16(a.v, b.v, acc[j], 0, 0, 0);
        }
    }

    const int rowq = q * 4;
#pragma unroll
    for (int r = 0; r < 4; r++) {
        int mrow = m0 + rowq + r;
        if (mrow >= N) continue;
#pragma unroll
        for (int j = 0; j < 8; j++) {
            int n = j * 16 + mr;
            uvb[(size_t)mrow * 128 + n] = f2bf(acc[j][r] + cb2[n]);
        }
    }
}

// ---------------- layer-2 finish: out = mean_agg(u) + v, fp32 ----------------
// uvb rows: [u(64) | v(64)] bf16; 8 lanes/node
__global__ __launch_bounds__(256) void gather_out_bf(const unsigned short* __restrict__ uvb,
                                                     const unsigned* __restrict__ row_start,
                                                     const unsigned* __restrict__ csr_src,
                                                     float* __restrict__ out, int N) {
    int gid = blockIdx.x * 256 + threadIdx.x;
    int node = gid >> 3;
    if (node >= N) return;
    int f = (threadIdx.x & 7) * 8;  // elem offset into u half
    unsigned s0 = row_start[node], s1 = row_start[node + 1];
    float acc[8];
#pragma unroll
    for (int i = 0; i < 8; i++) acc[i] = 0.f;
    unsigned i = s0;
    for (; i + 2 <= s1; i += 2) {
        unsigned sa = csr_src[i], sb = csr_src[i + 1];
        uint4 da = *(const uint4*)(uvb + (size_t)sa * 128 + f);
        uint4 db = *(const uint4*)(uvb + (size_t)sb * 128 + f);
        float l, h;
        unpack2(da.x, l, h); acc[0] += l; acc[1] += h;
        unpack2(da.y, l, h); acc[2] += l; acc[3] += h;
        unpack2(da.z, l, h); acc[4] += l; acc[5] += h;
        unpack2(da.w, l, h); acc[6] += l; acc[7] += h;
        unpack2(db.x, l, h); acc[0] += l; acc[1] += h;
        unpack2(db.y, l, h); acc[2] += l; acc[3] += h;
        unpack2(db.z, l, h); acc[4] += l; acc[5] += h;
        unpack2(db.w, l, h); acc[6] += l; acc[7] += h;
    }
    if (i < s1) {
        unsigned sa = csr_src[i];
        uint4 da = *(const uint4*)(uvb + (size_t)sa * 128 + f);
        float l, h;
        unpack2(da.x, l, h); acc[0] += l; acc[1] += h;
        unpack2(da.y, l, h); acc[2] += l; acc[3] += h;
        unpack2(da.z, l, h); acc[4] += l; acc[5] += h;
        unpack2(da.w, l, h); acc[6] += l; acc[7] += h;
    }
    float inv = (s1 > s0) ? 1.0f / (float)(s1 - s0) : 0.f;
    uint4 dv = *(const uint4*)(uvb + (size_t)node * 128 + 64 + f);
    float vv[8];
    unpack2(dv.x, vv[0], vv[1]);
    unpack2(dv.y, vv[2], vv[3]);
    unpack2(dv.z, vv[4], vv[5]);
    unpack2(dv.w, vv[6], vv[7]);
    float4 o0 = make_float4(acc[0] * inv + vv[0], acc[1] * inv + vv[1],
                            acc[2] * inv + vv[2], acc[3] * inv + vv[3]);
    float4 o1 = make_float4(acc[4] * inv + vv[4], acc[5] * inv + vv[5],
                            acc[6] * inv + vv[6], acc[7] * inv + vv[7]);
    *(float4*)(out + (size_t)node * 64 + f) = o0;
    *(float4*)(out + (size_t)node * 64 + f + 4) = o1;
}

extern "C" void kernel_launch(void* const* d_in, const int* in_sizes, int n_in,
                              void* d_out, int out_size, void* d_ws, size_t ws_size,
                              hipStream_t stream) {
    const float* x     = (const float*)d_in[0];
    const int*   edge  = (const int*)d_in[1];
    const float* W1l   = (const float*)d_in[2];
    const float* b1    = (const float*)d_in[3];
    const float* W1r   = (const float*)d_in[4];
    const float* gamma = (const float*)d_in[5];
    const float* beta  = (const float*)d_in[6];
    const float* mean  = (const float*)d_in[7];
    const float* var   = (const float*)d_in[8];
    const float* W2l   = (const float*)d_in[9];
    const float* b2    = (const float*)d_in[10];
    const float* W2r   = (const float*)d_in[11];

    const int N = in_sizes[0] / FEAT;
    const int E = in_sizes[1] / 2;
    const int* srcI = edge;
    const int* dstI = edge + E;

    // ws layout (bf16 buffers are N*128 ushorts each):
    unsigned short* aggb = (unsigned short*)d_ws;      // also uvb (reused layer 2)
    unsigned short* hb   = aggb + (size_t)N * 128;
    unsigned short* xb   = hb + (size_t)N * 128;
    unsigned short* Wb1  = xb + (size_t)N * 128;       // 128*256
    unsigned short* Wb2  = Wb1 + 128 * 256;            // 128*128
    float* bnsc = (float*)(Wb2 + 128 * 128);           // 128
    float* bnsh = bnsc + 128;                          // 128
    float* cb2  = bnsh + 128;                          // 128
    unsigned* degc      = (unsigned*)(cb2 + 128);      // N*CSTRIDE
    unsigned* row_start = degc + (size_t)N * CSTRIDE;  // N+1
    unsigned* rank      = row_start + (N + 1);         // E
    unsigned* partials  = rank + E;                    // 1024
    unsigned* csr_src   = partials + 1024;             // E

    float* outp = (float*)d_out;
    const int nb = (N + 255) / 256;

    hipMemsetAsync(degc, 0, (size_t)N * CSTRIDE * sizeof(unsigned), stream);

    prep_all<<<128, 256, 0, stream>>>(W1l, W1r, W2l, W2r, b1, gamma, beta, mean, var, b2,
                                      Wb1, Wb2, bnsc, bnsh, cb2);
    {
        long long total8 = (long long)N * 128 / 8;
        convert_x<<<(int)((total8 + 255) / 256), 256, 0, stream>>>(x, xb, total8);
    }
    count_rank<<<(E + 255) / 256, 256, 0, stream>>>(dstI, E, degc, rank);
    scan_block<<<nb, 256, 0, stream>>>(degc, row_start, partials, N);
    scan_partials<<<1, 1024, 0, stream>>>(partials, nb);
    scan_finish<<<nb, 256, 0, stream>>>(row_start, partials, N, E);
    fill_csr<<<(E + 255) / 256, 256, 0, stream>>>(srcI, dstI, E, row_start, rank, csr_src);

    // layer 1
    gather_mean_bf<<<(N * 16 + 255) / 256, 256, 0, stream>>>(xb, row_start, csr_src, aggb, N);
    sage1_mfma<<<(N + 63) / 64, 256, 0, stream>>>(aggb, xb, Wb1, bnsc, bnsh, hb, N);

    // layer 2: transform (u|v) then gather-mean(u)+v
    gemm_uv_mfma<<<(N + 63) / 64, 256, 0, stream>>>(hb, Wb2, cb2, aggb, N);
    gather_out_bf<<<(N * 8 + 255) / 256, 256, 0, stream>>>(aggb, row_start, csr_src, outp, N);
}

// Round 6
// 388.396 us; speedup vs baseline: 14.6985x; 1.0900x over previous
//
#include <hip/hip_runtime.h>

#define FEAT 128
#define BN_EPS 1e-5f
#define CSTRIDE 16   // one degree counter per 64B line

typedef __attribute__((ext_vector_type(8))) short s8frag;
typedef __attribute__((ext_vector_type(4))) float f4frag;

union FragU { uint4 u; s8frag v; };

__device__ __forceinline__ unsigned short f2bf(float f) {
    unsigned u = __float_as_uint(f);
    unsigned r = (u + 0x7fffu + ((u >> 16) & 1u)) >> 16;
    return (unsigned short)r;
}
__device__ __forceinline__ void unpack2(unsigned d, float& lo, float& hi) {
    lo = __uint_as_float(d << 16);
    hi = __uint_as_float(d & 0xffff0000u);
}

// ---------------- prep: bf16 weights + BN constants --------------------------
// Wb1[n][k] n<128,k<256: k<128 -> W1l[n][k], else W1r[n][k-128]
// Wb2[n][k] n<128,k<128: n<64 -> W2l[n][k],  else W2r[n-64][k]
__global__ void prep_all(const float* __restrict__ W1l, const float* __restrict__ W1r,
                         const float* __restrict__ W2l, const float* __restrict__ W2r,
                         const float* __restrict__ b1, const float* __restrict__ g,
                         const float* __restrict__ bt, const float* __restrict__ mu,
                         const float* __restrict__ var, const float* __restrict__ b2,
                         unsigned short* __restrict__ Wb1, unsigned short* __restrict__ Wb2,
                         float* __restrict__ bnsc, float* __restrict__ bnsh,
                         float* __restrict__ cb2) {
    int tid = blockIdx.x * blockDim.x + threadIdx.x;
    if (tid < 128 * 256) {
        int n = tid >> 8, k = tid & 255;
        float w = (k < 128) ? W1l[n * 128 + k] : W1r[n * 128 + (k - 128)];
        Wb1[tid] = f2bf(w);
    }
    if (tid < 128 * 128) {
        int n = tid >> 7, k = tid & 127;
        float w = (n < 64) ? W2l[n * 128 + k] : W2r[(n - 64) * 128 + k];
        Wb2[tid] = f2bf(w);
    }
    if (tid < 128) {
        float sc = rsqrtf(var[tid] + BN_EPS) * g[tid];
        bnsc[tid] = sc;
        bnsh[tid] = sc * (b1[tid] - mu[tid]) + bt[tid];
        cb2[tid] = (tid < 64) ? 0.f : b2[tid - 64];
    }
}

// ---------------- x -> bf16 (8 elems/thread) ---------------------------------
__global__ void convert_x(const float* __restrict__ x, unsigned short* __restrict__ xb,
                          long long total8) {
    long long t = (long long)blockIdx.x * blockDim.x + threadIdx.x;
    if (t >= total8) return;
    const float4* src = (const float4*)(x) + t * 2;
    float4 a = src[0], b = src[1];
    uint4 o;
    o.x = f2bf(a.x) | ((unsigned)f2bf(a.y) << 16);
    o.y = f2bf(a.z) | ((unsigned)f2bf(a.w) << 16);
    o.z = f2bf(b.x) | ((unsigned)f2bf(b.y) << 16);
    o.w = f2bf(b.z) | ((unsigned)f2bf(b.w) << 16);
    ((uint4*)xb)[t] = o;
}

// ---------------- fused degree count + per-edge rank -------------------------
__global__ void count_rank(const int* __restrict__ dst, int E,
                           unsigned* __restrict__ degc, unsigned* __restrict__ rank) {
    int e = blockIdx.x * blockDim.x + threadIdx.x;
    if (e >= E) return;
    rank[e] = atomicAdd(&degc[(size_t)dst[e] * CSTRIDE], 1u);
}

// ---------------- hierarchical exclusive scan over padded degc ---------------
__global__ void scan_block(const unsigned* __restrict__ degc, unsigned* __restrict__ excl,
                           unsigned* __restrict__ partials, int N) {
    __shared__ unsigned buf[256];
    int i = blockIdx.x * 256 + threadIdx.x;
    unsigned v = (i < N) ? degc[(size_t)i * CSTRIDE] : 0u;
    buf[threadIdx.x] = v;
    __syncthreads();
    for (int off = 1; off < 256; off <<= 1) {
        unsigned t = (threadIdx.x >= (unsigned)off) ? buf[threadIdx.x - off] : 0u;
        __syncthreads();
        buf[threadIdx.x] += t;
        __syncthreads();
    }
    if (i < N) excl[i] = buf[threadIdx.x] - v;
    if (threadIdx.x == 255) partials[blockIdx.x] = buf[255];
}

__global__ void scan_partials(unsigned* __restrict__ partials, int nb) {
    __shared__ unsigned buf[1024];
    unsigned v = ((int)threadIdx.x < nb) ? partials[threadIdx.x] : 0u;
    buf[threadIdx.x] = v;
    __syncthreads();
    for (int off = 1; off < 1024; off <<= 1) {
        unsigned t = (threadIdx.x >= (unsigned)off) ? buf[threadIdx.x - off] : 0u;
        __syncthreads();
        buf[threadIdx.x] += t;
        __syncthreads();
    }
    if ((int)threadIdx.x < nb) partials[threadIdx.x] = buf[threadIdx.x] - v;
}

__global__ void scan_finish(unsigned* __restrict__ row_start,
                            const unsigned* __restrict__ partials, int N, int E) {
    int i = blockIdx.x * blockDim.x + threadIdx.x;
    if (i < N) row_start[i] = row_start[i] + partials[i >> 8];
    if (i == 0) row_start[N] = (unsigned)E;
}

// ---------------- CSR fill: atomic-free --------------------------------------
__global__ void fill_csr(const int* __restrict__ src, const int* __restrict__ dst, int E,
                         const unsigned* __restrict__ row_start,
                         const unsigned* __restrict__ rank,
                         unsigned* __restrict__ csr_src) {
    int e = blockIdx.x * blockDim.x + threadIdx.x;
    if (e >= E) return;
    csr_src[row_start[dst[e]] + rank[e]] = (unsigned)src[e];
}

// ---------------- FUSED: gather-mean + layer1 GEMM/BN/ReLU + layer2 GEMM -----
// 64 nodes/block, 256 threads (4 waves), LDS: As 16KB (swizzled), Bs 32KB.
// uv rows out: [u(64)|v(64)] bf16.
__global__ __launch_bounds__(256) void sage_fused(
    const unsigned short* __restrict__ xb,
    const unsigned* __restrict__ row_start,
    const unsigned* __restrict__ csr_src,
    const unsigned short* __restrict__ Wb1,   // [128][256]
    const unsigned short* __restrict__ Wb2,   // [128][128]
    const float* __restrict__ bnsc, const float* __restrict__ bnsh,
    const float* __restrict__ cb2,
    unsigned short* __restrict__ uvb, int N)
{
    __shared__ __align__(16) unsigned short As[64 * 128];   // 16 KB
    __shared__ __align__(16) unsigned short Bs[128 * 128];  // 32 KB
    uint4* AsV = (uint4*)As;
    uint4* BsV = (uint4*)Bs;

    const int tid = threadIdx.x;
    const int wave = tid >> 6;
    const int lane = tid & 63;
    const int mr = lane & 15;
    const int q = lane >> 4;
    const int m0 = blockIdx.x * 64;
    const int mw = m0 + wave * 16 + mr;       // this lane's A-row
    const bool mv = mw < N;

    // ---- prefetch x-part A-frags (k = 128..255) into registers ----
    FragU ax[4];
#pragma unroll
    for (int kc4 = 0; kc4 < 4; kc4++) {
        ax[kc4].u = make_uint4(0u, 0u, 0u, 0u);
        if (mv) ax[kc4].u = *(const uint4*)(xb + (size_t)mw * 128 + kc4 * 32 + q * 8);
    }

    // ---- stage Bs <- Wb1 columns 0..127 (swizzled chunks) ----
#pragma unroll
    for (int i = 0; i < 8; i++) {
        int gch = tid + i * 256;
        int n = gch >> 4, c = gch & 15;
        BsV[n * 16 + (c ^ (n & 15))] = *(const uint4*)(Wb1 + (size_t)n * 256 + c * 8);
    }

    // ---- gather-mean into As: 4 groups x 16 nodes, 16 lanes/node ----
    const int gl = tid >> 4;     // node within group
    const int fc = tid & 15;     // feature chunk (8 bf16)
    const int f = fc * 8;
    for (int g = 0; g < 4; g++) {
        int nl = g * 16 + gl;
        int node = m0 + nl;
        unsigned s0 = 0, s1 = 0;
        if (node < N) { s0 = row_start[node]; s1 = row_start[node + 1]; }
        float acc[8];
#pragma unroll
        for (int i = 0; i < 8; i++) acc[i] = 0.f;
        unsigned i = s0;
        for (; i + 2 <= s1; i += 2) {
            unsigned sa = csr_src[i], sb = csr_src[i + 1];
            uint4 da = *(const uint4*)(xb + (size_t)sa * 128 + f);
            uint4 db = *(const uint4*)(xb + (size_t)sb * 128 + f);
            float l, h;
            unpack2(da.x, l, h); acc[0] += l; acc[1] += h;
            unpack2(da.y, l, h); acc[2] += l; acc[3] += h;
            unpack2(da.z, l, h); acc[4] += l; acc[5] += h;
            unpack2(da.w, l, h); acc[6] += l; acc[7] += h;
            unpack2(db.x, l, h); acc[0] += l; acc[1] += h;
            unpack2(db.y, l, h); acc[2] += l; acc[3] += h;
            unpack2(db.z, l, h); acc[4] += l; acc[5] += h;
            unpack2(db.w, l, h); acc[6] += l; acc[7] += h;
        }
        if (i < s1) {
            unsigned sa = csr_src[i];
            uint4 da = *(const uint4*)(xb + (size_t)sa * 128 + f);
            float l, h;
            unpack2(da.x, l, h); acc[0] += l; acc[1] += h;
            unpack2(da.y, l, h); acc[2] += l; acc[3] += h;
            unpack2(da.z, l, h); acc[4] += l; acc[5] += h;
            unpack2(da.w, l, h); acc[6] += l; acc[7] += h;
        }
        float inv = (s1 > s0) ? 1.0f / (float)(s1 - s0) : 0.f;
        uint4 o;
        o.x = f2bf(acc[0] * inv) | ((unsigned)f2bf(acc[1] * inv) << 16);
        o.y = f2bf(acc[2] * inv) | ((unsigned)f2bf(acc[3] * inv) << 16);
        o.z = f2bf(acc[4] * inv) | ((unsigned)f2bf(acc[5] * inv) << 16);
        o.w = f2bf(acc[6] * inv) | ((unsigned)f2bf(acc[7] * inv) << 16);
        AsV[nl * 16 + (fc ^ (nl & 15))] = o;
    }
    __syncthreads();   // As + Bs(half0) ready

    // ---- phase 2a: k = 0..127, A from As(LDS), B from Bs(LDS) ----
    f4frag acc[8];
#pragma unroll
    for (int j = 0; j < 8; j++)
#pragma unroll
        for (int r = 0; r < 4; r++) acc[j][r] = 0.f;

    const int arow = (wave * 16 + mr) * 16;
#pragma unroll
    for (int kc4 = 0; kc4 < 4; kc4++) {
        FragU a;
        a.u = AsV[arow + ((kc4 * 4 + q) ^ mr)];
#pragma unroll
        for (int j = 0; j < 8; j++) {
            FragU b;
            b.u = BsV[(j * 16 + mr) * 16 + ((kc4 * 4 + q) ^ mr)];
            acc[j] = __builtin_amdgcn_mfma_f32_16x16x32_bf16(a.v, b.v, acc[j], 0, 0, 0);
        }
    }
    __syncthreads();   // everyone done with Bs(half0)

    // ---- stage Bs <- Wb1 columns 128..255 ----
#pragma unroll
    for (int i = 0; i < 8; i++) {
        int gch = tid + i * 256;
        int n = gch >> 4, c = gch & 15;
        BsV[n * 16 + (c ^ (n & 15))] = *(const uint4*)(Wb1 + (size_t)n * 256 + 128 + c * 8);
    }
    __syncthreads();   // Bs(half1) ready

    // ---- phase 2b: k = 128..255, A from registers, B from Bs(LDS) ----
#pragma unroll
    for (int kc4 = 0; kc4 < 4; kc4++) {
#pragma unroll
        for (int j = 0; j < 8; j++) {
            FragU b;
            b.u = BsV[(j * 16 + mr) * 16 + ((kc4 * 4 + q) ^ mr)];
            acc[j] = __builtin_amdgcn_mfma_f32_16x16x32_bf16(ax[kc4].v, b.v, acc[j], 0, 0, 0);
        }
    }

    // ---- epilogue 1: BN+ReLU -> bf16 h, transposed into As (A-layout) ----
#pragma unroll
    for (int j = 0; j < 8; j++) {
        int n = j * 16 + mr;
        float sc = bnsc[n], sh = bnsh[n];
        int cn = n >> 3;
#pragma unroll
        for (int r = 0; r < 4; r++) {
            int ml = wave * 16 + q * 4 + r;
            float v = fmaxf(acc[j][r] * sc + sh, 0.f);
            As[(ml * 16 + (cn ^ (ml & 15))) * 8 + (n & 7)] = f2bf(v);
        }
    }
    __syncthreads();   // h in As; everyone done with Bs(half1)

    // ---- stage Bs <- Wb2 ----
#pragma unroll
    for (int i = 0; i < 8; i++) {
        int gch = tid + i * 256;
        int n = gch >> 4, c = gch & 15;
        BsV[n * 16 + (c ^ (n & 15))] = *(const uint4*)(Wb2 + (size_t)n * 128 + c * 8);
    }
    __syncthreads();   // Bs(W2) ready

    // ---- phase 3: uv = h @ Wb2^T ----
#pragma unroll
    for (int j = 0; j < 8; j++)
#pragma unroll
        for (int r = 0; r < 4; r++) acc[j][r] = 0.f;
#pragma unroll
    for (int kc4 = 0; kc4 < 4; kc4++) {
        FragU a;
        a.u = AsV[arow + ((kc4 * 4 + q) ^ mr)];
#pragma unroll
        for (int j = 0; j < 8; j++) {
            FragU b;
            b.u = BsV[(j * 16 + mr) * 16 + ((kc4 * 4 + q) ^ mr)];
            acc[j] = __builtin_amdgcn_mfma_f32_16x16x32_bf16(a.v, b.v, acc[j], 0, 0, 0);
        }
    }

    // ---- epilogue 2: + cb2, bf16 store to uvb ----
#pragma unroll
    for (int j = 0; j < 8; j++) {
        int n = j * 16 + mr;
        float cb = cb2[n];
#pragma unroll
        for (int r = 0; r < 4; r++) {
            int mrow = m0 + wave * 16 + q * 4 + r;
            if (mrow < N)
                uvb[(size_t)mrow * 128 + n] = f2bf(acc[j][r] + cb);
        }
    }
}

// ---------------- layer-2 finish: out = mean_agg(u) + v, fp32 ----------------
__global__ __launch_bounds__(256) void gather_out_bf(const unsigned short* __restrict__ uvb,
                                                     const unsigned* __restrict__ row_start,
                                                     const unsigned* __restrict__ csr_src,
                                                     float* __restrict__ out, int N) {
    int gid = blockIdx.x * 256 + threadIdx.x;
    int node = gid >> 3;
    if (node >= N) return;
    int f = (threadIdx.x & 7) * 8;
    unsigned s0 = row_start[node], s1 = row_start[node + 1];
    float acc[8];
#pragma unroll
    for (int i = 0; i < 8; i++) acc[i] = 0.f;
    unsigned i = s0;
    for (; i + 2 <= s1; i += 2) {
        unsigned sa = csr_src[i], sb = csr_src[i + 1];
        uint4 da = *(const uint4*)(uvb + (size_t)sa * 128 + f);
        uint4 db = *(const uint4*)(uvb + (size_t)sb * 128 + f);
        float l, h;
        unpack2(da.x, l, h); acc[0] += l; acc[1] += h;
        unpack2(da.y, l, h); acc[2] += l; acc[3] += h;
        unpack2(da.z, l, h); acc[4] += l; acc[5] += h;
        unpack2(da.w, l, h); acc[6] += l; acc[7] += h;
        unpack2(db.x, l, h); acc[0] += l; acc[1] += h;
        unpack2(db.y, l, h); acc[2] += l; acc[3] += h;
        unpack2(db.z, l, h); acc[4] += l; acc[5] += h;
        unpack2(db.w, l, h); acc[6] += l; acc[7] += h;
    }
    if (i < s1) {
        unsigned sa = csr_src[i];
        uint4 da = *(const uint4*)(uvb + (size_t)sa * 128 + f);
        float l, h;
        unpack2(da.x, l, h); acc[0] += l; acc[1] += h;
        unpack2(da.y, l, h); acc[2] += l; acc[3] += h;
        unpack2(da.z, l, h); acc[4] += l; acc[5] += h;
        unpack2(da.w, l, h); acc[6] += l; acc[7] += h;
    }
    float inv = (s1 > s0) ? 1.0f / (float)(s1 - s0) : 0.f;
    uint4 dv = *(const uint4*)(uvb + (size_t)node * 128 + 64 + f);
    float vv[8];
    unpack2(dv.x, vv[0], vv[1]);
    unpack2(dv.y, vv[2], vv[3]);
    unpack2(dv.z, vv[4], vv[5]);
    unpack2(dv.w, vv[6], vv[7]);
    float4 o0 = make_float4(acc[0] * inv + vv[0], acc[1] * inv + vv[1],
                            acc[2] * inv + vv[2], acc[3] * inv + vv[3]);
    float4 o1 = make_float4(acc[4] * inv + vv[4], acc[5] * inv + vv[5],
                            acc[6] * inv + vv[6], acc[7] * inv + vv[7]);
    *(float4*)(out + (size_t)node * 64 + f) = o0;
    *(float4*)(out + (size_t)node * 64 + f + 4) = o1;
}

extern "C" void kernel_launch(void* const* d_in, const int* in_sizes, int n_in,
                              void* d_out, int out_size, void* d_ws, size_t ws_size,
                              hipStream_t stream) {
    const float* x     = (const float*)d_in[0];
    const int*   edge  = (const int*)d_in[1];
    const float* W1l   = (const float*)d_in[2];
    const float* b1    = (const float*)d_in[3];
    const float* W1r   = (const float*)d_in[4];
    const float* gamma = (const float*)d_in[5];
    const float* beta  = (const float*)d_in[6];
    const float* mean  = (const float*)d_in[7];
    const float* var   = (const float*)d_in[8];
    const float* W2l   = (const float*)d_in[9];
    const float* b2    = (const float*)d_in[10];
    const float* W2r   = (const float*)d_in[11];

    const int N = in_sizes[0] / FEAT;
    const int E = in_sizes[1] / 2;
    const int* srcI = edge;
    const int* dstI = edge + E;

    // ws layout:
    unsigned short* uvb = (unsigned short*)d_ws;       // N*128
    unsigned short* xb  = uvb + (size_t)N * 128;       // N*128
    unsigned short* Wb1 = xb + (size_t)N * 128;        // 128*256
    unsigned short* Wb2 = Wb1 + 128 * 256;             // 128*128
    float* bnsc = (float*)(Wb2 + 128 * 128);           // 128
    float* bnsh = bnsc + 128;                          // 128
    float* cb2  = bnsh + 128;                          // 128
    unsigned* degc      = (unsigned*)(cb2 + 128);      // N*CSTRIDE
    unsigned* row_start = degc + (size_t)N * CSTRIDE;  // N+1
    unsigned* rank      = row_start + (N + 1);         // E
    unsigned* partials  = rank + E;                    // 1024
    unsigned* csr_src   = partials + 1024;             // E

    float* outp = (float*)d_out;
    const int nb = (N + 255) / 256;

    hipMemsetAsync(degc, 0, (size_t)N * CSTRIDE * sizeof(unsigned), stream);

    prep_all<<<128, 256, 0, stream>>>(W1l, W1r, W2l, W2r, b1, gamma, beta, mean, var, b2,
                                      Wb1, Wb2, bnsc, bnsh, cb2);
    {
        long long total8 = (long long)N * 128 / 8;
        convert_x<<<(int)((total8 + 255) / 256), 256, 0, stream>>>(x, xb, total8);
    }
    count_rank<<<(E + 255) / 256, 256, 0, stream>>>(dstI, E, degc, rank);
    scan_block<<<nb, 256, 0, stream>>>(degc, row_start, partials, N);
    scan_partials<<<1, 1024, 0, stream>>>(partials, nb);
    scan_finish<<<nb, 256, 0, stream>>>(row_start, partials, N, E);
    fill_csr<<<(E + 255) / 256, 256, 0, stream>>>(srcI, dstI, E, row_start, rank, csr_src);

    // fused: gather-mean(x) + layer1 (GEMM+BN+ReLU) + layer2 transform -> uvb
    sage_fused<<<(N + 63) / 64, 256, 0, stream>>>(xb, row_start, csr_src, Wb1, Wb2,
                                                  bnsc, bnsh, cb2, uvb, N);
    // layer-2 finish: gather-mean(u) + v -> out
    gather_out_bf<<<(N * 8 + 255) / 256, 256, 0, stream>>>(uvb, row_start, csr_src, outp, N);
}

// Round 7
// 349.486 us; speedup vs baseline: 16.3350x; 1.1113x over previous
//
#include <hip/hip_runtime.h>

#define FEAT 128
#define BN_EPS 1e-5f
#define CSTRIDE 16   // one degree counter per 64B line

typedef __attribute__((ext_vector_type(8))) short s8frag;
typedef __attribute__((ext_vector_type(4))) float f4frag;

union FragU { uint4 u; s8frag v; };

__device__ __forceinline__ unsigned short f2bf(float f) {
    unsigned u = __float_as_uint(f);
    unsigned r = (u + 0x7fffu + ((u >> 16) & 1u)) >> 16;
    return (unsigned short)r;
}
__device__ __forceinline__ void unpack2(unsigned d, float& lo, float& hi) {
    lo = __uint_as_float(d << 16);
    hi = __uint_as_float(d & 0xffff0000u);
}
__device__ __forceinline__ void acc8(float* acc, uint4 d) {
    float l, h;
    unpack2(d.x, l, h); acc[0] += l; acc[1] += h;
    unpack2(d.y, l, h); acc[2] += l; acc[3] += h;
    unpack2(d.z, l, h); acc[4] += l; acc[5] += h;
    unpack2(d.w, l, h); acc[6] += l; acc[7] += h;
}

// ---------------- prep: bf16 weights + BN constants --------------------------
__global__ void prep_all(const float* __restrict__ W1l, const float* __restrict__ W1r,
                         const float* __restrict__ W2l, const float* __restrict__ W2r,
                         const float* __restrict__ b1, const float* __restrict__ g,
                         const float* __restrict__ bt, const float* __restrict__ mu,
                         const float* __restrict__ var, const float* __restrict__ b2,
                         unsigned short* __restrict__ Wb1, unsigned short* __restrict__ Wb2,
                         float* __restrict__ bnsc, float* __restrict__ bnsh,
                         float* __restrict__ cb2) {
    int tid = blockIdx.x * blockDim.x + threadIdx.x;
    if (tid < 128 * 256) {
        int n = tid >> 8, k = tid & 255;
        float w = (k < 128) ? W1l[n * 128 + k] : W1r[n * 128 + (k - 128)];
        Wb1[tid] = f2bf(w);
    }
    if (tid < 128 * 128) {
        int n = tid >> 7, k = tid & 127;
        float w = (n < 64) ? W2l[n * 128 + k] : W2r[(n - 64) * 128 + k];
        Wb2[tid] = f2bf(w);
    }
    if (tid < 128) {
        float sc = rsqrtf(var[tid] + BN_EPS) * g[tid];
        bnsc[tid] = sc;
        bnsh[tid] = sc * (b1[tid] - mu[tid]) + bt[tid];
        cb2[tid] = (tid < 64) ? 0.f : b2[tid - 64];
    }
}

// ---------------- x -> bf16 (8 elems/thread) ---------------------------------
__global__ void convert_x(const float* __restrict__ x, unsigned short* __restrict__ xb,
                          long long total8) {
    long long t = (long long)blockIdx.x * blockDim.x + threadIdx.x;
    if (t >= total8) return;
    const float4* src = (const float4*)(x) + t * 2;
    float4 a = src[0], b = src[1];
    uint4 o;
    o.x = f2bf(a.x) | ((unsigned)f2bf(a.y) << 16);
    o.y = f2bf(a.z) | ((unsigned)f2bf(a.w) << 16);
    o.z = f2bf(b.x) | ((unsigned)f2bf(b.y) << 16);
    o.w = f2bf(b.z) | ((unsigned)f2bf(b.w) << 16);
    ((uint4*)xb)[t] = o;
}

// ---------------- fused degree count + per-edge rank -------------------------
__global__ void count_rank(const int* __restrict__ dst, int E,
                           unsigned* __restrict__ degc, unsigned* __restrict__ rank) {
    int e = blockIdx.x * blockDim.x + threadIdx.x;
    if (e >= E) return;
    rank[e] = atomicAdd(&degc[(size_t)dst[e] * CSTRIDE], 1u);
}

// ---------------- hierarchical exclusive scan over padded degc ---------------
__global__ void scan_block(const unsigned* __restrict__ degc, unsigned* __restrict__ excl,
                           unsigned* __restrict__ partials, int N) {
    __shared__ unsigned buf[256];
    int i = blockIdx.x * 256 + threadIdx.x;
    unsigned v = (i < N) ? degc[(size_t)i * CSTRIDE] : 0u;
    buf[threadIdx.x] = v;
    __syncthreads();
    for (int off = 1; off < 256; off <<= 1) {
        unsigned t = (threadIdx.x >= (unsigned)off) ? buf[threadIdx.x - off] : 0u;
        __syncthreads();
        buf[threadIdx.x] += t;
        __syncthreads();
    }
    if (i < N) excl[i] = buf[threadIdx.x] - v;
    if (threadIdx.x == 255) partials[blockIdx.x] = buf[255];
}

__global__ void scan_partials(unsigned* __restrict__ partials, int nb) {
    __shared__ unsigned buf[1024];
    unsigned v = ((int)threadIdx.x < nb) ? partials[threadIdx.x] : 0u;
    buf[threadIdx.x] = v;
    __syncthreads();
    for (int off = 1; off < 1024; off <<= 1) {
        unsigned t = (threadIdx.x >= (unsigned)off) ? buf[threadIdx.x - off] : 0u;
        __syncthreads();
        buf[threadIdx.x] += t;
        __syncthreads();
    }
    if ((int)threadIdx.x < nb) partials[threadIdx.x] = buf[threadIdx.x] - v;
}

__global__ void scan_finish(unsigned* __restrict__ row_start,
                            const unsigned* __restrict__ partials, int N, int E) {
    int i = blockIdx.x * blockDim.x + threadIdx.x;
    if (i < N) row_start[i] = row_start[i] + partials[i >> 8];
    if (i == 0) row_start[N] = (unsigned)E;
}

// ---------------- CSR fill: atomic-free --------------------------------------
__global__ void fill_csr(const int* __restrict__ src, const int* __restrict__ dst, int E,
                         const unsigned* __restrict__ row_start,
                         const unsigned* __restrict__ rank,
                         unsigned* __restrict__ csr_src) {
    int e = blockIdx.x * blockDim.x + threadIdx.x;
    if (e >= E) return;
    csr_src[row_start[dst[e]] + rank[e]] = (unsigned)src[e];
}

// ---------------- gather + mean over 128 bf16 feats: 16 lanes/node, unroll 4 -
__global__ __launch_bounds__(256) void gather_mean_bf(const unsigned short* __restrict__ xb,
                                                      const unsigned* __restrict__ row_start,
                                                      const unsigned* __restrict__ csr_src,
                                                      unsigned short* __restrict__ aggb, int N) {
    int gid = blockIdx.x * 256 + threadIdx.x;
    int node = gid >> 4;
    if (node >= N) return;
    int f = (threadIdx.x & 15) * 8;
    unsigned s0 = row_start[node], s1 = row_start[node + 1];
    float acc[8];
#pragma unroll
    for (int i = 0; i < 8; i++) acc[i] = 0.f;
    unsigned i = s0;
    for (; i + 4 <= s1; i += 4) {
        unsigned sa = csr_src[i], sb = csr_src[i + 1];
        unsigned sc = csr_src[i + 2], sd = csr_src[i + 3];
        uint4 da = *(const uint4*)(xb + (size_t)sa * 128 + f);
        uint4 db = *(const uint4*)(xb + (size_t)sb * 128 + f);
        uint4 dc = *(const uint4*)(xb + (size_t)sc * 128 + f);
        uint4 dd = *(const uint4*)(xb + (size_t)sd * 128 + f);
        acc8(acc, da); acc8(acc, db); acc8(acc, dc); acc8(acc, dd);
    }
    for (; i < s1; i++) {
        unsigned sa = csr_src[i];
        uint4 da = *(const uint4*)(xb + (size_t)sa * 128 + f);
        acc8(acc, da);
    }
    float inv = (s1 > s0) ? 1.0f / (float)(s1 - s0) : 0.f;
    uint4 o;
    o.x = f2bf(acc[0] * inv) | ((unsigned)f2bf(acc[1] * inv) << 16);
    o.y = f2bf(acc[2] * inv) | ((unsigned)f2bf(acc[3] * inv) << 16);
    o.z = f2bf(acc[4] * inv) | ((unsigned)f2bf(acc[5] * inv) << 16);
    o.w = f2bf(acc[6] * inv) | ((unsigned)f2bf(acc[7] * inv) << 16);
    *(uint4*)(aggb + (size_t)node * 128 + f) = o;
}

// ---------------- dense: layer1 GEMM+BN/ReLU + layer2 GEMM, LDS weights ------
// 64 rows/block, 256 threads. A-frags from global registers; Bs staged 3x.
__global__ __launch_bounds__(256) void sage_dense(
    const unsigned short* __restrict__ aggb,
    const unsigned short* __restrict__ xb,
    const unsigned short* __restrict__ Wb1,   // [128][256]
    const unsigned short* __restrict__ Wb2,   // [128][128]
    const float* __restrict__ bnsc, const float* __restrict__ bnsh,
    const float* __restrict__ cb2,
    unsigned short* __restrict__ uvb, int N)
{
    __shared__ __align__(16) unsigned short As[64 * 128];   // 16 KB (h transpose)
    __shared__ __align__(16) unsigned short Bs[128 * 128];  // 32 KB
    uint4* AsV = (uint4*)As;
    uint4* BsV = (uint4*)Bs;

    const int tid = threadIdx.x;
    const int wave = tid >> 6;
    const int lane = tid & 63;
    const int mr = lane & 15;
    const int q = lane >> 4;
    const int m0 = blockIdx.x * 64;
    const int mw = m0 + wave * 16 + mr;
    const bool mv = mw < N;

    // ---- A-frags for layer 1: agg part (k 0..127) + x part (k 128..255) ----
    FragU ag[4], ax[4];
#pragma unroll
    for (int kc4 = 0; kc4 < 4; kc4++) {
        ag[kc4].u = make_uint4(0u, 0u, 0u, 0u);
        ax[kc4].u = make_uint4(0u, 0u, 0u, 0u);
        if (mv) {
            ag[kc4].u = *(const uint4*)(aggb + (size_t)mw * 128 + kc4 * 32 + q * 8);
            ax[kc4].u = *(const uint4*)(xb + (size_t)mw * 128 + kc4 * 32 + q * 8);
        }
    }

    // ---- stage Bs <- Wb1 k 0..127 (swizzled chunks) ----
#pragma unroll
    for (int i = 0; i < 8; i++) {
        int gch = tid + i * 256;
        int n = gch >> 4, c = gch & 15;
        BsV[n * 16 + (c ^ (n & 15))] = *(const uint4*)(Wb1 + (size_t)n * 256 + c * 8);
    }
    __syncthreads();

    f4frag acc[8];
#pragma unroll
    for (int j = 0; j < 8; j++)
#pragma unroll
        for (int r = 0; r < 4; r++) acc[j][r] = 0.f;

#pragma unroll
    for (int kc4 = 0; kc4 < 4; kc4++) {
#pragma unroll
        for (int j = 0; j < 8; j++) {
            FragU b;
            b.u = BsV[(j * 16 + mr) * 16 + ((kc4 * 4 + q) ^ mr)];
            acc[j] = __builtin_amdgcn_mfma_f32_16x16x32_bf16(ag[kc4].v, b.v, acc[j], 0, 0, 0);
        }
    }
    __syncthreads();   // done with Bs(half0)

    // ---- stage Bs <- Wb1 k 128..255 ----
#pragma unroll
    for (int i = 0; i < 8; i++) {
        int gch = tid + i * 256;
        int n = gch >> 4, c = gch & 15;
        BsV[n * 16 + (c ^ (n & 15))] = *(const uint4*)(Wb1 + (size_t)n * 256 + 128 + c * 8);
    }
    __syncthreads();

#pragma unroll
    for (int kc4 = 0; kc4 < 4; kc4++) {
#pragma unroll
        for (int j = 0; j < 8; j++) {
            FragU b;
            b.u = BsV[(j * 16 + mr) * 16 + ((kc4 * 4 + q) ^ mr)];
            acc[j] = __builtin_amdgcn_mfma_f32_16x16x32_bf16(ax[kc4].v, b.v, acc[j], 0, 0, 0);
        }
    }

    // ---- epilogue 1: BN+ReLU -> bf16 h, transposed into As (A-layout) ----
#pragma unroll
    for (int j = 0; j < 8; j++) {
        int n = j * 16 + mr;
        float sc = bnsc[n], sh = bnsh[n];
        int cn = n >> 3;
#pragma unroll
        for (int r = 0; r < 4; r++) {
            int ml = wave * 16 + q * 4 + r;
            float v = fmaxf(acc[j][r] * sc + sh, 0.f);
            As[(ml * 16 + (cn ^ (ml & 15))) * 8 + (n & 7)] = f2bf(v);
        }
    }
    __syncthreads();   // h in As; all waves done with Bs(half1)

    // ---- stage Bs <- Wb2 ----
#pragma unroll
    for (int i = 0; i < 8; i++) {
        int gch = tid + i * 256;
        int n = gch >> 4, c = gch & 15;
        BsV[n * 16 + (c ^ (n & 15))] = *(const uint4*)(Wb2 + (size_t)n * 128 + c * 8);
    }
    __syncthreads();

    // ---- phase 3: uv = h @ Wb2^T ----
#pragma unroll
    for (int j = 0; j < 8; j++)
#pragma unroll
        for (int r = 0; r < 4; r++) acc[j][r] = 0.f;
    const int arow = (wave * 16 + mr) * 16;
#pragma unroll
    for (int kc4 = 0; kc4 < 4; kc4++) {
        FragU a;
        a.u = AsV[arow + ((kc4 * 4 + q) ^ mr)];
#pragma unroll
        for (int j = 0; j < 8; j++) {
            FragU b;
            b.u = BsV[(j * 16 + mr) * 16 + ((kc4 * 4 + q) ^ mr)];
            acc[j] = __builtin_amdgcn_mfma_f32_16x16x32_bf16(a.v, b.v, acc[j], 0, 0, 0);
        }
    }

    // ---- epilogue 2: + cb2, bf16 store to uvb ----
#pragma unroll
    for (int j = 0; j < 8; j++) {
        int n = j * 16 + mr;
        float cb = cb2[n];
#pragma unroll
        for (int r = 0; r < 4; r++) {
            int mrow = m0 + wave * 16 + q * 4 + r;
            if (mrow < N)
                uvb[(size_t)mrow * 128 + n] = f2bf(acc[j][r] + cb);
        }
    }
}

// ---------------- layer-2 finish: out = mean_agg(u) + v, fp32, unroll 4 ------
__global__ __launch_bounds__(256) void gather_out_bf(const unsigned short* __restrict__ uvb,
                                                     const unsigned* __restrict__ row_start,
                                                     const unsigned* __restrict__ csr_src,
                                                     float* __restrict__ out, int N) {
    int gid = blockIdx.x * 256 + threadIdx.x;
    int node = gid >> 3;
    if (node >= N) return;
    int f = (threadIdx.x & 7) * 8;
    unsigned s0 = row_start[node], s1 = row_start[node + 1];
    float acc[8];
#pragma unroll
    for (int i = 0; i < 8; i++) acc[i] = 0.f;
    unsigned i = s0;
    for (; i + 4 <= s1; i += 4) {
        unsigned sa = csr_src[i], sb = csr_src[i + 1];
        unsigned sc = csr_src[i + 2], sd = csr_src[i + 3];
        uint4 da = *(const uint4*)(uvb + (size_t)sa * 128 + f);
        uint4 db = *(const uint4*)(uvb + (size_t)sb * 128 + f);
        uint4 dc = *(const uint4*)(uvb + (size_t)sc * 128 + f);
        uint4 dd = *(const uint4*)(uvb + (size_t)sd * 128 + f);
        acc8(acc, da); acc8(acc, db); acc8(acc, dc); acc8(acc, dd);
    }
    for (; i < s1; i++) {
        unsigned sa = csr_src[i];
        uint4 da = *(const uint4*)(uvb + (size_t)sa * 128 + f);
        acc8(acc, da);
    }
    float inv = (s1 > s0) ? 1.0f / (float)(s1 - s0) : 0.f;
    uint4 dv = *(const uint4*)(uvb + (size_t)node * 128 + 64 + f);
    float vv[8];
    unpack2(dv.x, vv[0], vv[1]);
    unpack2(dv.y, vv[2], vv[3]);
    unpack2(dv.z, vv[4], vv[5]);
    unpack2(dv.w, vv[6], vv[7]);
    float4 o0 = make_float4(acc[0] * inv + vv[0], acc[1] * inv + vv[1],
                            acc[2] * inv + vv[2], acc[3] * inv + vv[3]);
    float4 o1 = make_float4(acc[4] * inv + vv[4], acc[5] * inv + vv[5],
                            acc[6] * inv + vv[6], acc[7] * inv + vv[7]);
    *(float4*)(out + (size_t)node * 64 + f) = o0;
    *(float4*)(out + (size_t)node * 64 + f + 4) = o1;
}

extern "C" void kernel_launch(void* const* d_in, const int* in_sizes, int n_in,
                              void* d_out, int out_size, void* d_ws, size_t ws_size,
                              hipStream_t stream) {
    const float* x     = (const float*)d_in[0];
    const int*   edge  = (const int*)d_in[1];
    const float* W1l   = (const float*)d_in[2];
    const float* b1    = (const float*)d_in[3];
    const float* W1r   = (const float*)d_in[4];
    const float* gamma = (const float*)d_in[5];
    const float* beta  = (const float*)d_in[6];
    const float* mean  = (const float*)d_in[7];
    const float* var   = (const float*)d_in[8];
    const float* W2l   = (const float*)d_in[9];
    const float* b2    = (const float*)d_in[10];
    const float* W2r   = (const float*)d_in[11];

    const int N = in_sizes[0] / FEAT;
    const int E = in_sizes[1] / 2;
    const int* srcI = edge;
    const int* dstI = edge + E;

    // ws layout:
    unsigned short* uvb  = (unsigned short*)d_ws;      // N*128 (also aggb scratch ordering below)
    unsigned short* aggb = uvb + (size_t)N * 128;      // N*128
    unsigned short* xb   = aggb + (size_t)N * 128;     // N*128
    unsigned short* Wb1  = xb + (size_t)N * 128;       // 128*256
    unsigned short* Wb2  = Wb1 + 128 * 256;            // 128*128
    float* bnsc = (float*)(Wb2 + 128 * 128);           // 128
    float* bnsh = bnsc + 128;                          // 128
    float* cb2  = bnsh + 128;                          // 128
    unsigned* degc      = (unsigned*)(cb2 + 128);      // N*CSTRIDE
    unsigned* row_start = degc + (size_t)N * CSTRIDE;  // N+1
    unsigned* rank      = row_start + (N + 1);         // E
    unsigned* partials  = rank + E;                    // 1024
    unsigned* csr_src   = partials + 1024;             // E

    float* outp = (float*)d_out;
    const int nb = (N + 255) / 256;

    hipMemsetAsync(degc, 0, (size_t)N * CSTRIDE * sizeof(unsigned), stream);

    prep_all<<<128, 256, 0, stream>>>(W1l, W1r, W2l, W2r, b1, gamma, beta, mean, var, b2,
                                      Wb1, Wb2, bnsc, bnsh, cb2);
    {
        long long total8 = (long long)N * 128 / 8;
        convert_x<<<(int)((total8 + 255) / 256), 256, 0, stream>>>(x, xb, total8);
    }
    count_rank<<<(E + 255) / 256, 256, 0, stream>>>(dstI, E, degc, rank);
    scan_block<<<nb, 256, 0, stream>>>(degc, row_start, partials, N);
    scan_partials<<<1, 1024, 0, stream>>>(partials, nb);
    scan_finish<<<nb, 256, 0, stream>>>(row_start, partials, N, E);
    fill_csr<<<(E + 255) / 256, 256, 0, stream>>>(srcI, dstI, E, row_start, rank, csr_src);

    // layer 1 gather at full occupancy
    gather_mean_bf<<<(N * 16 + 255) / 256, 256, 0, stream>>>(xb, row_start, csr_src, aggb, N);
    // dense: layer1 GEMM+BN+ReLU + layer2 transform -> uvb
    sage_dense<<<(N + 63) / 64, 256, 0, stream>>>(aggb, xb, Wb1, Wb2, bnsc, bnsh, cb2, uvb, N);
    // layer-2 finish: gather-mean(u) + v -> out
    gather_out_bf<<<(N * 8 + 255) / 256, 256, 0, stream>>>(uvb, row_start, csr_src, outp, N);
}

// Round 8
// 346.464 us; speedup vs baseline: 16.4774x; 1.0087x over previous
//
#include <hip/hip_runtime.h>

#define FEAT 128
#define BN_EPS 1e-5f
#define CSTRIDE 16   // one degree counter per 64B line

typedef __attribute__((ext_vector_type(8))) short s8frag;
typedef __attribute__((ext_vector_type(4))) float f4frag;

union FragU { uint4 u; s8frag v; };

__device__ __forceinline__ unsigned short f2bf(float f) {
    unsigned u = __float_as_uint(f);
    unsigned r = (u + 0x7fffu + ((u >> 16) & 1u)) >> 16;
    return (unsigned short)r;
}
__device__ __forceinline__ void unpack2(unsigned d, float& lo, float& hi) {
    lo = __uint_as_float(d << 16);
    hi = __uint_as_float(d & 0xffff0000u);
}
__device__ __forceinline__ void acc8(float* acc, uint4 d) {
    float l, h;
    unpack2(d.x, l, h); acc[0] += l; acc[1] += h;
    unpack2(d.y, l, h); acc[2] += l; acc[3] += h;
    unpack2(d.z, l, h); acc[4] += l; acc[5] += h;
    unpack2(d.w, l, h); acc[6] += l; acc[7] += h;
}

// ---------------- prep: bf16 weights + BN constants --------------------------
__global__ void prep_all(const float* __restrict__ W1l, const float* __restrict__ W1r,
                         const float* __restrict__ W2l, const float* __restrict__ W2r,
                         const float* __restrict__ b1, const float* __restrict__ g,
                         const float* __restrict__ bt, const float* __restrict__ mu,
                         const float* __restrict__ var, const float* __restrict__ b2,
                         unsigned short* __restrict__ Wb1, unsigned short* __restrict__ Wb2,
                         float* __restrict__ bnsc, float* __restrict__ bnsh,
                         float* __restrict__ cb2) {
    int tid = blockIdx.x * blockDim.x + threadIdx.x;
    if (tid < 128 * 256) {
        int n = tid >> 8, k = tid & 255;
        float w = (k < 128) ? W1l[n * 128 + k] : W1r[n * 128 + (k - 128)];
        Wb1[tid] = f2bf(w);
    }
    if (tid < 128 * 128) {
        int n = tid >> 7, k = tid & 127;
        float w = (n < 64) ? W2l[n * 128 + k] : W2r[(n - 64) * 128 + k];
        Wb2[tid] = f2bf(w);
    }
    if (tid < 128) {
        float sc = rsqrtf(var[tid] + BN_EPS) * g[tid];
        bnsc[tid] = sc;
        bnsh[tid] = sc * (b1[tid] - mu[tid]) + bt[tid];
        cb2[tid] = (tid < 64) ? 0.f : b2[tid - 64];
    }
}

// ---------------- x -> bf16 (8 elems/thread) ---------------------------------
__global__ void convert_x(const float* __restrict__ x, unsigned short* __restrict__ xb,
                          long long total8) {
    long long t = (long long)blockIdx.x * blockDim.x + threadIdx.x;
    if (t >= total8) return;
    const float4* src = (const float4*)(x) + t * 2;
    float4 a = src[0], b = src[1];
    uint4 o;
    o.x = f2bf(a.x) | ((unsigned)f2bf(a.y) << 16);
    o.y = f2bf(a.z) | ((unsigned)f2bf(a.w) << 16);
    o.z = f2bf(b.x) | ((unsigned)f2bf(b.y) << 16);
    o.w = f2bf(b.z) | ((unsigned)f2bf(b.w) << 16);
    ((uint4*)xb)[t] = o;
}

// ---------------- degree count + per-edge rank: 8 edges/thread ---------------
__global__ void count_rank(const int* __restrict__ dst, int E,
                           unsigned* __restrict__ degc, unsigned* __restrict__ rank) {
    int base = (blockIdx.x * blockDim.x + threadIdx.x) * 8;
    if (base + 8 <= E) {
        int4 d0 = *(const int4*)(dst + base);
        int4 d1 = *(const int4*)(dst + base + 4);
        unsigned r0 = atomicAdd(&degc[(size_t)d0.x * CSTRIDE], 1u);
        unsigned r1 = atomicAdd(&degc[(size_t)d0.y * CSTRIDE], 1u);
        unsigned r2 = atomicAdd(&degc[(size_t)d0.z * CSTRIDE], 1u);
        unsigned r3 = atomicAdd(&degc[(size_t)d0.w * CSTRIDE], 1u);
        unsigned r4 = atomicAdd(&degc[(size_t)d1.x * CSTRIDE], 1u);
        unsigned r5 = atomicAdd(&degc[(size_t)d1.y * CSTRIDE], 1u);
        unsigned r6 = atomicAdd(&degc[(size_t)d1.z * CSTRIDE], 1u);
        unsigned r7 = atomicAdd(&degc[(size_t)d1.w * CSTRIDE], 1u);
        *(uint4*)(rank + base)     = make_uint4(r0, r1, r2, r3);
        *(uint4*)(rank + base + 4) = make_uint4(r4, r5, r6, r7);
    } else {
        for (int e = base; e < E; e++)
            rank[e] = atomicAdd(&degc[(size_t)dst[e] * CSTRIDE], 1u);
    }
}

// ---------------- hierarchical exclusive scan over padded degc ---------------
__global__ void scan_block(const unsigned* __restrict__ degc, unsigned* __restrict__ excl,
                           unsigned* __restrict__ partials, int N) {
    __shared__ unsigned buf[256];
    int i = blockIdx.x * 256 + threadIdx.x;
    unsigned v = (i < N) ? degc[(size_t)i * CSTRIDE] : 0u;
    buf[threadIdx.x] = v;
    __syncthreads();
    for (int off = 1; off < 256; off <<= 1) {
        unsigned t = (threadIdx.x >= (unsigned)off) ? buf[threadIdx.x - off] : 0u;
        __syncthreads();
        buf[threadIdx.x] += t;
        __syncthreads();
    }
    if (i < N) excl[i] = buf[threadIdx.x] - v;
    if (threadIdx.x == 255) partials[blockIdx.x] = buf[255];
}

__global__ void scan_partials(unsigned* __restrict__ partials, int nb) {
    __shared__ unsigned buf[1024];
    unsigned v = ((int)threadIdx.x < nb) ? partials[threadIdx.x] : 0u;
    buf[threadIdx.x] = v;
    __syncthreads();
    for (int off = 1; off < 1024; off <<= 1) {
        unsigned t = (threadIdx.x >= (unsigned)off) ? buf[threadIdx.x - off] : 0u;
        __syncthreads();
        buf[threadIdx.x] += t;
        __syncthreads();
    }
    if ((int)threadIdx.x < nb) partials[threadIdx.x] = buf[threadIdx.x] - v;
}

__global__ void scan_finish(unsigned* __restrict__ row_start,
                            const unsigned* __restrict__ partials, int N, int E) {
    int i = blockIdx.x * blockDim.x + threadIdx.x;
    if (i < N) row_start[i] = row_start[i] + partials[i >> 8];
    if (i == 0) row_start[N] = (unsigned)E;
}

// ---------------- CSR fill: atomic-free, 4 edges/thread ----------------------
__global__ void fill_csr(const int* __restrict__ src, const int* __restrict__ dst, int E,
                         const unsigned* __restrict__ row_start,
                         const unsigned* __restrict__ rank,
                         unsigned* __restrict__ csr_src) {
    int base = (blockIdx.x * blockDim.x + threadIdx.x) * 4;
    if (base + 4 <= E) {
        int4 d = *(const int4*)(dst + base);
        int4 s = *(const int4*)(src + base);
        uint4 r = *(const uint4*)(rank + base);
        unsigned p0 = row_start[d.x] + r.x;
        unsigned p1 = row_start[d.y] + r.y;
        unsigned p2 = row_start[d.z] + r.z;
        unsigned p3 = row_start[d.w] + r.w;
        csr_src[p0] = (unsigned)s.x;
        csr_src[p1] = (unsigned)s.y;
        csr_src[p2] = (unsigned)s.z;
        csr_src[p3] = (unsigned)s.w;
    } else {
        for (int e = base; e < E; e++)
            csr_src[row_start[dst[e]] + rank[e]] = (unsigned)src[e];
    }
}

// ---------------- gather + mean over 128 bf16 feats: 16 lanes/node, unroll 4 -
__global__ __launch_bounds__(256) void gather_mean_bf(const unsigned short* __restrict__ xb,
                                                      const unsigned* __restrict__ row_start,
                                                      const unsigned* __restrict__ csr_src,
                                                      unsigned short* __restrict__ aggb, int N) {
    int gid = blockIdx.x * 256 + threadIdx.x;
    int node = gid >> 4;
    if (node >= N) return;
    int f = (threadIdx.x & 15) * 8;
    unsigned s0 = row_start[node], s1 = row_start[node + 1];
    float acc[8];
#pragma unroll
    for (int i = 0; i < 8; i++) acc[i] = 0.f;
    unsigned i = s0;
    for (; i + 4 <= s1; i += 4) {
        unsigned sa = csr_src[i], sb = csr_src[i + 1];
        unsigned sc = csr_src[i + 2], sd = csr_src[i + 3];
        uint4 da = *(const uint4*)(xb + (size_t)sa * 128 + f);
        uint4 db = *(const uint4*)(xb + (size_t)sb * 128 + f);
        uint4 dc = *(const uint4*)(xb + (size_t)sc * 128 + f);
        uint4 dd = *(const uint4*)(xb + (size_t)sd * 128 + f);
        acc8(acc, da); acc8(acc, db); acc8(acc, dc); acc8(acc, dd);
    }
    for (; i < s1; i++) {
        unsigned sa = csr_src[i];
        uint4 da = *(const uint4*)(xb + (size_t)sa * 128 + f);
        acc8(acc, da);
    }
    float inv = (s1 > s0) ? 1.0f / (float)(s1 - s0) : 0.f;
    uint4 o;
    o.x = f2bf(acc[0] * inv) | ((unsigned)f2bf(acc[1] * inv) << 16);
    o.y = f2bf(acc[2] * inv) | ((unsigned)f2bf(acc[3] * inv) << 16);
    o.z = f2bf(acc[4] * inv) | ((unsigned)f2bf(acc[5] * inv) << 16);
    o.w = f2bf(acc[6] * inv) | ((unsigned)f2bf(acc[7] * inv) << 16);
    *(uint4*)(aggb + (size_t)node * 128 + f) = o;
}

// ---------------- dense: layer1 GEMM+BN/ReLU + layer2 GEMM, LDS weights ------
__global__ __launch_bounds__(256) void sage_dense(
    const unsigned short* __restrict__ aggb,
    const unsigned short* __restrict__ xb,
    const unsigned short* __restrict__ Wb1,   // [128][256]
    const unsigned short* __restrict__ Wb2,   // [128][128]
    const float* __restrict__ bnsc, const float* __restrict__ bnsh,
    const float* __restrict__ cb2,
    unsigned short* __restrict__ uvb, int N)
{
    __shared__ __align__(16) unsigned short As[64 * 128];   // 16 KB (h transpose)
    __shared__ __align__(16) unsigned short Bs[128 * 128];  // 32 KB
    uint4* AsV = (uint4*)As;
    uint4* BsV = (uint4*)Bs;

    const int tid = threadIdx.x;
    const int wave = tid >> 6;
    const int lane = tid & 63;
    const int mr = lane & 15;
    const int q = lane >> 4;
    const int m0 = blockIdx.x * 64;
    const int mw = m0 + wave * 16 + mr;
    const bool mv = mw < N;

    FragU ag[4], ax[4];
#pragma unroll
    for (int kc4 = 0; kc4 < 4; kc4++) {
        ag[kc4].u = make_uint4(0u, 0u, 0u, 0u);
        ax[kc4].u = make_uint4(0u, 0u, 0u, 0u);
        if (mv) {
            ag[kc4].u = *(const uint4*)(aggb + (size_t)mw * 128 + kc4 * 32 + q * 8);
            ax[kc4].u = *(const uint4*)(xb + (size_t)mw * 128 + kc4 * 32 + q * 8);
        }
    }

#pragma unroll
    for (int i = 0; i < 8; i++) {
        int gch = tid + i * 256;
        int n = gch >> 4, c = gch & 15;
        BsV[n * 16 + (c ^ (n & 15))] = *(const uint4*)(Wb1 + (size_t)n * 256 + c * 8);
    }
    __syncthreads();

    f4frag acc[8];
#pragma unroll
    for (int j = 0; j < 8; j++)
#pragma unroll
        for (int r = 0; r < 4; r++) acc[j][r] = 0.f;

#pragma unroll
    for (int kc4 = 0; kc4 < 4; kc4++) {
#pragma unroll
        for (int j = 0; j < 8; j++) {
            FragU b;
            b.u = BsV[(j * 16 + mr) * 16 + ((kc4 * 4 + q) ^ mr)];
            acc[j] = __builtin_amdgcn_mfma_f32_16x16x32_bf16(ag[kc4].v, b.v, acc[j], 0, 0, 0);
        }
    }
    __syncthreads();

#pragma unroll
    for (int i = 0; i < 8; i++) {
        int gch = tid + i * 256;
        int n = gch >> 4, c = gch & 15;
        BsV[n * 16 + (c ^ (n & 15))] = *(const uint4*)(Wb1 + (size_t)n * 256 + 128 + c * 8);
    }
    __syncthreads();

#pragma unroll
    for (int kc4 = 0; kc4 < 4; kc4++) {
#pragma unroll
        for (int j = 0; j < 8; j++) {
            FragU b;
            b.u = BsV[(j * 16 + mr) * 16 + ((kc4 * 4 + q) ^ mr)];
            acc[j] = __builtin_amdgcn_mfma_f32_16x16x32_bf16(ax[kc4].v, b.v, acc[j], 0, 0, 0);
        }
    }

#pragma unroll
    for (int j = 0; j < 8; j++) {
        int n = j * 16 + mr;
        float sc = bnsc[n], sh = bnsh[n];
        int cn = n >> 3;
#pragma unroll
        for (int r = 0; r < 4; r++) {
            int ml = wave * 16 + q * 4 + r;
            float v = fmaxf(acc[j][r] * sc + sh, 0.f);
            As[(ml * 16 + (cn ^ (ml & 15))) * 8 + (n & 7)] = f2bf(v);
        }
    }
    __syncthreads();

#pragma unroll
    for (int i = 0; i < 8; i++) {
        int gch = tid + i * 256;
        int n = gch >> 4, c = gch & 15;
        BsV[n * 16 + (c ^ (n & 15))] = *(const uint4*)(Wb2 + (size_t)n * 128 + c * 8);
    }
    __syncthreads();

#pragma unroll
    for (int j = 0; j < 8; j++)
#pragma unroll
        for (int r = 0; r < 4; r++) acc[j][r] = 0.f;
    const int arow = (wave * 16 + mr) * 16;
#pragma unroll
    for (int kc4 = 0; kc4 < 4; kc4++) {
        FragU a;
        a.u = AsV[arow + ((kc4 * 4 + q) ^ mr)];
#pragma unroll
        for (int j = 0; j < 8; j++) {
            FragU b;
            b.u = BsV[(j * 16 + mr) * 16 + ((kc4 * 4 + q) ^ mr)];
            acc[j] = __builtin_amdgcn_mfma_f32_16x16x32_bf16(a.v, b.v, acc[j], 0, 0, 0);
        }
    }

#pragma unroll
    for (int j = 0; j < 8; j++) {
        int n = j * 16 + mr;
        float cb = cb2[n];
#pragma unroll
        for (int r = 0; r < 4; r++) {
            int mrow = m0 + wave * 16 + q * 4 + r;
            if (mrow < N)
                uvb[(size_t)mrow * 128 + n] = f2bf(acc[j][r] + cb);
        }
    }
}

// ---------------- layer-2 finish: out = mean_agg(u) + v, fp32, unroll 4 ------
__global__ __launch_bounds__(256) void gather_out_bf(const unsigned short* __restrict__ uvb,
                                                     const unsigned* __restrict__ row_start,
                                                     const unsigned* __restrict__ csr_src,
                                                     float* __restrict__ out, int N) {
    int gid = blockIdx.x * 256 + threadIdx.x;
    int node = gid >> 3;
    if (node >= N) return;
    int f = (threadIdx.x & 7) * 8;
    unsigned s0 = row_start[node], s1 = row_start[node + 1];
    float acc[8];
#pragma unroll
    for (int i = 0; i < 8; i++) acc[i] = 0.f;
    unsigned i = s0;
    for (; i + 4 <= s1; i += 4) {
        unsigned sa = csr_src[i], sb = csr_src[i + 1];
        unsigned sc = csr_src[i + 2], sd = csr_src[i + 3];
        uint4 da = *(const uint4*)(uvb + (size_t)sa * 128 + f);
        uint4 db = *(const uint4*)(uvb + (size_t)sb * 128 + f);
        uint4 dc = *(const uint4*)(uvb + (size_t)sc * 128 + f);
        uint4 dd = *(const uint4*)(uvb + (size_t)sd * 128 + f);
        acc8(acc, da); acc8(acc, db); acc8(acc, dc); acc8(acc, dd);
    }
    for (; i < s1; i++) {
        unsigned sa = csr_src[i];
        uint4 da = *(const uint4*)(uvb + (size_t)sa * 128 + f);
        acc8(acc, da);
    }
    float inv = (s1 > s0) ? 1.0f / (float)(s1 - s0) : 0.f;
    uint4 dv = *(const uint4*)(uvb + (size_t)node * 128 + 64 + f);
    float vv[8];
    unpack2(dv.x, vv[0], vv[1]);
    unpack2(dv.y, vv[2], vv[3]);
    unpack2(dv.z, vv[4], vv[5]);
    unpack2(dv.w, vv[6], vv[7]);
    float4 o0 = make_float4(acc[0] * inv + vv[0], acc[1] * inv + vv[1],
                            acc[2] * inv + vv[2], acc[3] * inv + vv[3]);
    float4 o1 = make_float4(acc[4] * inv + vv[4], acc[5] * inv + vv[5],
                            acc[6] * inv + vv[6], acc[7] * inv + vv[7]);
    *(float4*)(out + (size_t)node * 64 + f) = o0;
    *(float4*)(out + (size_t)node * 64 + f + 4) = o1;
}

extern "C" void kernel_launch(void* const* d_in, const int* in_sizes, int n_in,
                              void* d_out, int out_size, void* d_ws, size_t ws_size,
                              hipStream_t stream) {
    const float* x     = (const float*)d_in[0];
    const int*   edge  = (const int*)d_in[1];
    const float* W1l   = (const float*)d_in[2];
    const float* b1    = (const float*)d_in[3];
    const float* W1r   = (const float*)d_in[4];
    const float* gamma = (const float*)d_in[5];
    const float* beta  = (const float*)d_in[6];
    const float* mean  = (const float*)d_in[7];
    const float* var   = (const float*)d_in[8];
    const float* W2l   = (const float*)d_in[9];
    const float* b2    = (const float*)d_in[10];
    const float* W2r   = (const float*)d_in[11];

    const int N = in_sizes[0] / FEAT;
    const int E = in_sizes[1] / 2;
    const int* srcI = edge;
    const int* dstI = edge + E;

    unsigned short* uvb  = (unsigned short*)d_ws;      // N*128
    unsigned short* aggb = uvb + (size_t)N * 128;      // N*128
    unsigned short* xb   = aggb + (size_t)N * 128;     // N*128
    unsigned short* Wb1  = xb + (size_t)N * 128;       // 128*256
    unsigned short* Wb2  = Wb1 + 256 * 128;            // 128*128
    float* bnsc = (float*)(Wb2 + 128 * 128);           // 128
    float* bnsh = bnsc + 128;                          // 128
    float* cb2  = bnsh + 128;                          // 128
    unsigned* degc      = (unsigned*)(cb2 + 128);      // N*CSTRIDE
    unsigned* row_start = degc + (size_t)N * CSTRIDE;  // N+1
    unsigned* rank      = row_start + (N + 1);         // E
    unsigned* partials  = rank + E;                    // 1024
    unsigned* csr_src   = partials + 1024;             // E

    float* outp = (float*)d_out;
    const int nb = (N + 255) / 256;

    hipMemsetAsync(degc, 0, (size_t)N * CSTRIDE * sizeof(unsigned), stream);

    prep_all<<<128, 256, 0, stream>>>(W1l, W1r, W2l, W2r, b1, gamma, beta, mean, var, b2,
                                      Wb1, Wb2, bnsc, bnsh, cb2);
    {
        long long total8 = (long long)N * 128 / 8;
        convert_x<<<(int)((total8 + 255) / 256), 256, 0, stream>>>(x, xb, total8);
    }
    {
        int threads8 = (E + 7) / 8;
        count_rank<<<(threads8 + 255) / 256, 256, 0, stream>>>(dstI, E, degc, rank);
    }
    scan_block<<<nb, 256, 0, stream>>>(degc, row_start, partials, N);
    scan_partials<<<1, 1024, 0, stream>>>(partials, nb);
    scan_finish<<<nb, 256, 0, stream>>>(row_start, partials, N, E);
    {
        int threads4 = (E + 3) / 4;
        fill_csr<<<(threads4 + 255) / 256, 256, 0, stream>>>(srcI, dstI, E, row_start, rank, csr_src);
    }

    gather_mean_bf<<<(N * 16 + 255) / 256, 256, 0, stream>>>(xb, row_start, csr_src, aggb, N);
    sage_dense<<<(N + 63) / 64, 256, 0, stream>>>(aggb, xb, Wb1, Wb2, bnsc, bnsh, cb2, uvb, N);
    gather_out_bf<<<(N * 8 + 255) / 256, 256, 0, stream>>>(uvb, row_start, csr_src, outp, N);
}